// Round 1
// baseline (637.417 us; speedup 1.0000x reference)
//
#include <hip/hip_runtime.h>
#include <math.h>

#define Bb  64
#define Tt  256
#define Cc  384
#define NHh 6
#define HDd 64
#define N3C 1152

// ---------------- RoPE table: cos/sin[t][i], t<256, i<32 ----------------
__global__ void rope_table_k(float* __restrict__ cosT, float* __restrict__ sinT) {
    int idx = blockIdx.x * 256 + threadIdx.x;   // 8192 total
    int t = idx >> 5;
    int i = idx & 31;
    float inv = powf(10000.0f, -(float)i / 32.0f);   // base^(-2i/64)
    float ang = (float)t * inv;
    cosT[idx] = cosf(ang);
    sinT[idx] = sinf(ang);
}

// ---------------- Tiled fp32 GEMM: C = A[MxK] * B[KxN] ----------------
// BM=BN=128, BK=16, 256 threads, 8x8 micro-tile per thread.
// ROPE=true epilogue: applies RoPE to q/k, scales q by hd^-0.5, writes
// q,k,v transposed to [B, nh, T, hd]. ROPE=false: plain store to outC.
#define BM 128
#define BN 128
#define BK 16

template<bool ROPE>
__global__ __launch_bounds__(256)
void gemm_k(const float* __restrict__ A, const float* __restrict__ Bw,
            int M, int N, int K,
            const float* __restrict__ cosT, const float* __restrict__ sinT,
            float* __restrict__ outQ, float* __restrict__ outK2,
            float* __restrict__ outV, float* __restrict__ outC)
{
    __shared__ float As[BK][BM + 4];   // k-major (transposed) A tile
    __shared__ float Bs[BK][BN + 4];

    const int n0  = blockIdx.x * BN;
    const int m0  = blockIdx.y * BM;
    const int tid = threadIdx.x;
    const int tx  = tid & 15;          // col group (8 cols)
    const int ty  = tid >> 4;          // row group (8 rows)

    float acc[8][8];
#pragma unroll
    for (int i = 0; i < 8; ++i)
#pragma unroll
        for (int j = 0; j < 8; ++j) acc[i][j] = 0.f;

    // staging maps
    const int ar0 = tid >> 2;          // A row within tile (0..63), +64 for 2nd
    const int ak0 = tid & 3;           // A k-float4 (0..3)
    const int bk0 = tid >> 5;          // B k-row (0..7), +8 for 2nd
    const int bn0 = tid & 31;          // B n-float4 (0..31)

    for (int kc = 0; kc < K; kc += BK) {
        float4 a0 = *(const float4*)&A[(size_t)(m0 + ar0)      * K + kc + ak0 * 4];
        float4 a1 = *(const float4*)&A[(size_t)(m0 + 64 + ar0) * K + kc + ak0 * 4];
        float4 b0 = *(const float4*)&Bw[(size_t)(kc + bk0)     * N + n0 + bn0 * 4];
        float4 b1 = *(const float4*)&Bw[(size_t)(kc + 8 + bk0) * N + n0 + bn0 * 4];
        __syncthreads();   // previous tile fully consumed
        As[ak0*4+0][ar0] = a0.x; As[ak0*4+1][ar0] = a0.y;
        As[ak0*4+2][ar0] = a0.z; As[ak0*4+3][ar0] = a0.w;
        As[ak0*4+0][64+ar0] = a1.x; As[ak0*4+1][64+ar0] = a1.y;
        As[ak0*4+2][64+ar0] = a1.z; As[ak0*4+3][64+ar0] = a1.w;
        *(float4*)&Bs[bk0][bn0*4]     = b0;
        *(float4*)&Bs[bk0 + 8][bn0*4] = b1;
        __syncthreads();
#pragma unroll
        for (int kk = 0; kk < BK; ++kk) {
            float a[8], b[8];
            *(float4*)&a[0] = *(const float4*)&As[kk][ty*8];
            *(float4*)&a[4] = *(const float4*)&As[kk][ty*8 + 4];
            *(float4*)&b[0] = *(const float4*)&Bs[kk][tx*8];
            *(float4*)&b[4] = *(const float4*)&Bs[kk][tx*8 + 4];
#pragma unroll
            for (int i = 0; i < 8; ++i)
#pragma unroll
                for (int j = 0; j < 8; ++j)
                    acc[i][j] = fmaf(a[i], b[j], acc[i][j]);
        }
    }

    if (!ROPE) {
#pragma unroll
        for (int i = 0; i < 8; ++i) {
            int mrow = m0 + ty*8 + i;
            float* dst = &outC[(size_t)mrow * N + n0 + tx*8];
            *(float4*)&dst[0] = make_float4(acc[i][0], acc[i][1], acc[i][2], acc[i][3]);
            *(float4*)&dst[4] = make_float4(acc[i][4], acc[i][5], acc[i][6], acc[i][7]);
        }
    } else {
        const int ncol  = n0 + tx*8;
        const int which = ncol / Cc;            // 0=q 1=k 2=v (uniform per block)
        const int hc    = (ncol % Cc) / HDd;
        const int d0    = ncol % HDd;           // multiple of 8
        float* dstbase = (which == 0) ? outQ : (which == 1) ? outK2 : outV;
#pragma unroll
        for (int i = 0; i < 8; ++i) {
            int mrow = m0 + ty*8 + i;
            int bb = mrow >> 8, t = mrow & 255;
            float v[8];
#pragma unroll
            for (int j = 0; j < 8; ++j) v[j] = acc[i][j];
            if (which < 2) {
#pragma unroll
                for (int pg = 0; pg < 4; ++pg) {
                    int pi = (d0 >> 1) + pg;
                    float cv = cosT[t*32 + pi], sv = sinT[t*32 + pi];
                    float e = v[2*pg], o = v[2*pg+1];
                    v[2*pg]   = e * cv - o * sv;
                    v[2*pg+1] = o * cv + e * sv;
                }
                if (which == 0) {
#pragma unroll
                    for (int j = 0; j < 8; ++j) v[j] *= 0.125f;  // hd^-0.5
                }
            }
            float* dst = &dstbase[(size_t)(((bb*NHh) + hc)*Tt + t)*HDd + d0];
            *(float4*)&dst[0] = make_float4(v[0], v[1], v[2], v[3]);
            *(float4*)&dst[4] = make_float4(v[4], v[5], v[6], v[7]);
        }
    }
}

// ---------------- Flash attention, fp32, causal ----------------
// 1 wave per block. Block = one (b,h) x 64-q-row slab. Q pre-scaled.
#define CHUNK 32
__global__ __launch_bounds__(64)
void attn_k(const float* __restrict__ Q, const float* __restrict__ Kv,
            const float* __restrict__ Vv, float* __restrict__ O)
{
    __shared__ float Kc[CHUNK][HDd];
    __shared__ float Vc[CHUNK][HDd];

    const int idx  = blockIdx.x;
    const int qb   = idx & 3;          // q slab
    const int bh   = idx >> 2;         // b*NH + h
    const int lane = threadIdx.x;      // 0..63
    const int tq   = qb*64 + lane;

    const float* qrow = Q + (size_t)(bh*Tt + tq) * HDd;
    float q[HDd];
#pragma unroll
    for (int j = 0; j < 16; ++j)
        *(float4*)&q[j*4] = *(const float4*)&qrow[j*4];

    float o[HDd];
#pragma unroll
    for (int j = 0; j < HDd; ++j) o[j] = 0.f;
    float m = -1e30f, l = 0.f;

    const float* kbase = Kv + (size_t)bh * Tt * HDd;
    const float* vbase = Vv + (size_t)bh * Tt * HDd;
    const int nch = 2 * (qb + 1);      // 32-key chunks covering 0..64(qb+1)-1

    for (int c = 0; c < nch; ++c) {
        const float4* ksrc = (const float4*)(kbase + c*CHUNK*HDd);
        const float4* vsrc = (const float4*)(vbase + c*CHUNK*HDd);
        float4* kds = (float4*)&Kc[0][0];
        float4* vds = (float4*)&Vc[0][0];
#pragma unroll
        for (int j = 0; j < 8; ++j) {          // 512 float4 / 64 lanes
            kds[j*64 + lane] = ksrc[j*64 + lane];
            vds[j*64 + lane] = vsrc[j*64 + lane];
        }
        __syncthreads();

        float s[CHUNK];
#pragma unroll
        for (int kk = 0; kk < CHUNK; ++kk) {
            int kg = c*CHUNK + kk;
            float acc = 0.f;
#pragma unroll
            for (int j = 0; j < 16; ++j) {
                float4 kv = *(const float4*)&Kc[kk][j*4];
                acc = fmaf(q[j*4+0], kv.x, acc);
                acc = fmaf(q[j*4+1], kv.y, acc);
                acc = fmaf(q[j*4+2], kv.z, acc);
                acc = fmaf(q[j*4+3], kv.w, acc);
            }
            s[kk] = (kg <= tq) ? acc : -1e30f;
        }

        float pm = s[0];
#pragma unroll
        for (int kk = 1; kk < CHUNK; ++kk) pm = fmaxf(pm, s[kk]);
        float nm   = fmaxf(m, pm);
        float resc = __expf(m - nm);
        l *= resc;
#pragma unroll
        for (int j = 0; j < HDd; ++j) o[j] *= resc;

#pragma unroll
        for (int kk = 0; kk < CHUNK; ++kk) {
            float p = __expf(s[kk] - nm);
            l += p;
#pragma unroll
            for (int j = 0; j < 16; ++j) {
                float4 vv = *(const float4*)&Vc[kk][j*4];
                o[j*4+0] = fmaf(p, vv.x, o[j*4+0]);
                o[j*4+1] = fmaf(p, vv.y, o[j*4+1]);
                o[j*4+2] = fmaf(p, vv.z, o[j*4+2]);
                o[j*4+3] = fmaf(p, vv.w, o[j*4+3]);
            }
        }
        m = nm;
        __syncthreads();
    }

    const float inv = 1.0f / l;
    const int bbat = bh / NHh, hh = bh % NHh;
    float* optr = O + (size_t)(bbat*Tt + tq) * Cc + hh*HDd;   // [B,T,C] layout
#pragma unroll
    for (int j = 0; j < 16; ++j) {
        *(float4*)&optr[j*4] = make_float4(o[j*4+0]*inv, o[j*4+1]*inv,
                                           o[j*4+2]*inv, o[j*4+3]*inv);
    }
}

// ---------------- launcher ----------------
extern "C" void kernel_launch(void* const* d_in, const int* in_sizes, int n_in,
                              void* d_out, int out_size, void* d_ws, size_t ws_size,
                              hipStream_t stream) {
    (void)in_sizes; (void)n_in; (void)out_size; (void)ws_size;
    const float* x      = (const float*)d_in[0];
    const float* w_attn = (const float*)d_in[1];
    const float* w_proj = (const float*)d_in[2];
    float* out = (float*)d_out;
    float* ws  = (float*)d_ws;

    const size_t SZ = (size_t)Bb * NHh * Tt * HDd;  // 6,291,456 floats
    float* cosT = ws;
    float* sinT = ws + 8192;
    float* Q    = ws + 16384;
    float* Kv   = Q + SZ;
    float* Vv   = Kv + SZ;
    float* AO   = Vv + SZ;     // attention output in [B,T,C]

    hipLaunchKernelGGL(rope_table_k, dim3(32), dim3(256), 0, stream, cosT, sinT);

    dim3 g1(N3C / BN, (Bb * Tt) / BM);  // (9, 128)
    hipLaunchKernelGGL((gemm_k<true>), g1, dim3(256), 0, stream,
                       x, w_attn, Bb * Tt, N3C, Cc,
                       cosT, sinT, Q, Kv, Vv, (float*)nullptr);

    hipLaunchKernelGGL(attn_k, dim3(Bb * NHh * 4), dim3(64), 0, stream,
                       Q, Kv, Vv, AO);

    dim3 g2(Cc / BN, (Bb * Tt) / BM);   // (3, 128)
    hipLaunchKernelGGL((gemm_k<false>), g2, dim3(256), 0, stream,
                       AO, w_proj, Bb * Tt, Cc, Cc,
                       (const float*)nullptr, (const float*)nullptr,
                       (float*)nullptr, (float*)nullptr, (float*)nullptr, out);
}

// Round 2
// 521.765 us; speedup vs baseline: 1.2217x; 1.2217x over previous
//
#include <hip/hip_runtime.h>
#include <math.h>

#define Bb  64
#define Tt  256
#define Cc  384
#define NHh 6
#define HDd 64
#define N3C 1152

// ---------------- RoPE table: cos/sin[t][i], t<256, i<32 ----------------
__global__ void rope_table_k(float* __restrict__ cosT, float* __restrict__ sinT) {
    int idx = blockIdx.x * 256 + threadIdx.x;   // 8192 total
    int t = idx >> 5;
    int i = idx & 31;
    float inv = powf(10000.0f, -(float)i / 32.0f);   // base^(-2i/64)
    float ang = (float)t * inv;
    cosT[idx] = cosf(ang);
    sinT[idx] = sinf(ang);
}

// ---------------- Tiled fp32 GEMM: C = A[MxK] * B[KxN] ----------------
#define BM 128
#define BN 128
#define BK 16

template<bool ROPE>
__global__ __launch_bounds__(256)
void gemm_k(const float* __restrict__ A, const float* __restrict__ Bw,
            int M, int N, int K,
            const float* __restrict__ cosT, const float* __restrict__ sinT,
            float* __restrict__ outQ, float* __restrict__ outK2,
            float* __restrict__ outV, float* __restrict__ outC)
{
    __shared__ float As[BK][BM + 4];   // k-major (transposed) A tile
    __shared__ float Bs[BK][BN + 4];

    const int n0  = blockIdx.x * BN;
    const int m0  = blockIdx.y * BM;
    const int tid = threadIdx.x;
    const int tx  = tid & 15;          // col group (8 cols)
    const int ty  = tid >> 4;          // row group (8 rows)

    float acc[8][8];
#pragma unroll
    for (int i = 0; i < 8; ++i)
#pragma unroll
        for (int j = 0; j < 8; ++j) acc[i][j] = 0.f;

    const int ar0 = tid >> 2;          // A row within tile (0..63), +64 for 2nd
    const int ak0 = tid & 3;           // A k-float4 (0..3)
    const int bk0 = tid >> 5;          // B k-row (0..7), +8 for 2nd
    const int bn0 = tid & 31;          // B n-float4 (0..31)

    for (int kc = 0; kc < K; kc += BK) {
        float4 a0 = *(const float4*)&A[(size_t)(m0 + ar0)      * K + kc + ak0 * 4];
        float4 a1 = *(const float4*)&A[(size_t)(m0 + 64 + ar0) * K + kc + ak0 * 4];
        float4 b0 = *(const float4*)&Bw[(size_t)(kc + bk0)     * N + n0 + bn0 * 4];
        float4 b1 = *(const float4*)&Bw[(size_t)(kc + 8 + bk0) * N + n0 + bn0 * 4];
        __syncthreads();   // previous tile fully consumed
        As[ak0*4+0][ar0] = a0.x; As[ak0*4+1][ar0] = a0.y;
        As[ak0*4+2][ar0] = a0.z; As[ak0*4+3][ar0] = a0.w;
        As[ak0*4+0][64+ar0] = a1.x; As[ak0*4+1][64+ar0] = a1.y;
        As[ak0*4+2][64+ar0] = a1.z; As[ak0*4+3][64+ar0] = a1.w;
        *(float4*)&Bs[bk0][bn0*4]     = b0;
        *(float4*)&Bs[bk0 + 8][bn0*4] = b1;
        __syncthreads();
#pragma unroll
        for (int kk = 0; kk < BK; ++kk) {
            float a[8], b[8];
            *(float4*)&a[0] = *(const float4*)&As[kk][ty*8];
            *(float4*)&a[4] = *(const float4*)&As[kk][ty*8 + 4];
            *(float4*)&b[0] = *(const float4*)&Bs[kk][tx*8];
            *(float4*)&b[4] = *(const float4*)&Bs[kk][tx*8 + 4];
#pragma unroll
            for (int i = 0; i < 8; ++i)
#pragma unroll
                for (int j = 0; j < 8; ++j)
                    acc[i][j] = fmaf(a[i], b[j], acc[i][j]);
        }
    }

    if (!ROPE) {
#pragma unroll
        for (int i = 0; i < 8; ++i) {
            int mrow = m0 + ty*8 + i;
            float* dst = &outC[(size_t)mrow * N + n0 + tx*8];
            *(float4*)&dst[0] = make_float4(acc[i][0], acc[i][1], acc[i][2], acc[i][3]);
            *(float4*)&dst[4] = make_float4(acc[i][4], acc[i][5], acc[i][6], acc[i][7]);
        }
    } else {
        const int ncol  = n0 + tx*8;
        const int which = ncol / Cc;            // 0=q 1=k 2=v (uniform per block)
        const int hc    = (ncol % Cc) / HDd;
        const int d0    = ncol % HDd;           // multiple of 8
        float* dstbase = (which == 0) ? outQ : (which == 1) ? outK2 : outV;
#pragma unroll
        for (int i = 0; i < 8; ++i) {
            int mrow = m0 + ty*8 + i;
            int bb = mrow >> 8, t = mrow & 255;
            float v[8];
#pragma unroll
            for (int j = 0; j < 8; ++j) v[j] = acc[i][j];
            if (which < 2) {
#pragma unroll
                for (int pg = 0; pg < 4; ++pg) {
                    int pi = (d0 >> 1) + pg;
                    float cv = cosT[t*32 + pi], sv = sinT[t*32 + pi];
                    float e = v[2*pg], o = v[2*pg+1];
                    v[2*pg]   = e * cv - o * sv;
                    v[2*pg+1] = o * cv + e * sv;
                }
                if (which == 0) {
#pragma unroll
                    for (int j = 0; j < 8; ++j) v[j] *= 0.125f;  // hd^-0.5
                }
            }
            float* dst = &dstbase[(size_t)(((bb*NHh) + hc)*Tt + t)*HDd + d0];
            *(float4*)&dst[0] = make_float4(v[0], v[1], v[2], v[3]);
            *(float4*)&dst[4] = make_float4(v[4], v[5], v[6], v[7]);
        }
    }
}

// ---------------- Flash attention, fp32, causal — restructured ----------------
// 2 lanes per q-row (dims split 32+32), 32 q-rows per wave, 1 wave per block.
// Grid: B*NH*8 = 3072 blocks. K/V staged 16 keys/chunk via global_load_lds,
// double-buffered with counted vmcnt — no __syncthreads anywhere.
#define ACH 16

__device__ __forceinline__ void gll16(const float* g, float* l) {
    __builtin_amdgcn_global_load_lds(
        (const __attribute__((address_space(1))) void*)g,
        (__attribute__((address_space(3))) void*)l, 16, 0, 0);
}

__global__ __launch_bounds__(64)
void attn_k(const float* __restrict__ Q, const float* __restrict__ Kv,
            const float* __restrict__ Vv, float* __restrict__ O)
{
    __shared__ float sKV[2][2][ACH][HDd];   // [buf][K/V][key][dim] = 16 KB

    const int slab = blockIdx.x & 7;        // 32-row slab index
    const int bh   = blockIdx.x >> 3;       // b*NH + h
    const int lane = threadIdx.x;
    const int ro   = lane >> 1;             // row within slab (0..31)
    const int sub  = lane & 1;              // dim half (0/1)
    const int row  = slab * 32 + ro;        // q row (0..255)

    const float* kbase = Kv + (size_t)bh * Tt * HDd;
    const float* vbase = Vv + (size_t)bh * Tt * HDd;

    // q fragment: 32 dims
    float q[32];
    const float* qrow = Q + (size_t)(bh * Tt + row) * HDd + sub * 32;
#pragma unroll
    for (int j = 0; j < 8; ++j)
        *(float4*)&q[j * 4] = *(const float4*)&qrow[j * 4];

    float o[32];
#pragma unroll
    for (int j = 0; j < 32; ++j) o[j] = 0.f;
    float m = -1e30f, l = 0.f;

    const int nch = 2 * slab + 2;           // 16-key chunks covering 0..row_max

    // stage chunk 0 into buf 0: 4 issues K + 4 issues V, 1 KB each
#define STAGE(ch, buf)                                                        \
    {                                                                         \
        const float* kg_ = kbase + (ch) * ACH * HDd;                          \
        const float* vg_ = vbase + (ch) * ACH * HDd;                          \
        float* kl_ = &sKV[(buf)][0][0][0];                                    \
        float* vl_ = &sKV[(buf)][1][0][0];                                    \
        _Pragma("unroll")                                                     \
        for (int jj = 0; jj < 4; ++jj) {                                      \
            gll16(kg_ + jj * 256 + lane * 4, kl_ + jj * 256);                 \
            gll16(vg_ + jj * 256 + lane * 4, vl_ + jj * 256);                 \
        }                                                                     \
    }

    STAGE(0, 0)

    for (int c = 0; c < nch; ++c) {
        const int cur = c & 1;
        if (c + 1 < nch) {
            STAGE(c + 1, cur ^ 1)
            asm volatile("s_waitcnt vmcnt(8)" ::: "memory");  // chunk c landed
        } else {
            asm volatile("s_waitcnt vmcnt(0)" ::: "memory");
        }
        const float* Kc = &sKV[cur][0][0][0];
        const float* Vc = &sKV[cur][1][0][0];

        // ---- scores: 16 keys, 32-dim partial dot + shfl_xor(1) combine ----
        float s[ACH];
#pragma unroll
        for (int kk = 0; kk < ACH; ++kk) {
            const float* kr = Kc + kk * HDd + sub * 32;
            float a0 = 0.f, a1 = 0.f, a2 = 0.f, a3 = 0.f;
#pragma unroll
            for (int j = 0; j < 2; ++j) {
                float4 k0 = *(const float4*)&kr[j * 16 + 0];
                float4 k1 = *(const float4*)&kr[j * 16 + 4];
                float4 k2 = *(const float4*)&kr[j * 16 + 8];
                float4 k3 = *(const float4*)&kr[j * 16 + 12];
                const float* qq = &q[j * 16];
                a0 = fmaf(qq[0],  k0.x, a0); a0 = fmaf(qq[1],  k0.y, a0);
                a0 = fmaf(qq[2],  k0.z, a0); a0 = fmaf(qq[3],  k0.w, a0);
                a1 = fmaf(qq[4],  k1.x, a1); a1 = fmaf(qq[5],  k1.y, a1);
                a1 = fmaf(qq[6],  k1.z, a1); a1 = fmaf(qq[7],  k1.w, a1);
                a2 = fmaf(qq[8],  k2.x, a2); a2 = fmaf(qq[9],  k2.y, a2);
                a2 = fmaf(qq[10], k2.z, a2); a2 = fmaf(qq[11], k2.w, a2);
                a3 = fmaf(qq[12], k3.x, a3); a3 = fmaf(qq[13], k3.y, a3);
                a3 = fmaf(qq[14], k3.z, a3); a3 = fmaf(qq[15], k3.w, a3);
            }
            float acc = (a0 + a1) + (a2 + a3);
            acc += __shfl_xor(acc, 1);       // combine the two dim-halves
            s[kk] = (c * ACH + kk <= row) ? acc : -1e30f;
        }

        // ---- online softmax update ----
        float pm = s[0];
#pragma unroll
        for (int kk = 1; kk < ACH; ++kk) pm = fmaxf(pm, s[kk]);
        float nm   = fmaxf(m, pm);
        float resc = __expf(m - nm);
        l *= resc;
#pragma unroll
        for (int j = 0; j < 32; ++j) o[j] *= resc;

        // ---- PV accumulate ----
#pragma unroll
        for (int kk = 0; kk < ACH; ++kk) {
            float p = __expf(s[kk] - nm);
            l += p;
            const float* vr = Vc + kk * HDd + sub * 32;
#pragma unroll
            for (int j = 0; j < 8; ++j) {
                float4 vv = *(const float4*)&vr[j * 4];
                o[j*4+0] = fmaf(p, vv.x, o[j*4+0]);
                o[j*4+1] = fmaf(p, vv.y, o[j*4+1]);
                o[j*4+2] = fmaf(p, vv.z, o[j*4+2]);
                o[j*4+3] = fmaf(p, vv.w, o[j*4+3]);
            }
        }
        m = nm;
    }

    const float inv = 1.0f / l;
    const int bbat = bh / NHh, hh = bh % NHh;
    float* optr = O + (size_t)(bbat * Tt + row) * Cc + hh * HDd + sub * 32;
#pragma unroll
    for (int j = 0; j < 8; ++j)
        *(float4*)&optr[j * 4] = make_float4(o[j*4+0]*inv, o[j*4+1]*inv,
                                             o[j*4+2]*inv, o[j*4+3]*inv);
}

// ---------------- launcher ----------------
extern "C" void kernel_launch(void* const* d_in, const int* in_sizes, int n_in,
                              void* d_out, int out_size, void* d_ws, size_t ws_size,
                              hipStream_t stream) {
    (void)in_sizes; (void)n_in; (void)out_size; (void)ws_size;
    const float* x      = (const float*)d_in[0];
    const float* w_attn = (const float*)d_in[1];
    const float* w_proj = (const float*)d_in[2];
    float* out = (float*)d_out;
    float* ws  = (float*)d_ws;

    const size_t SZ = (size_t)Bb * NHh * Tt * HDd;  // 6,291,456 floats
    float* cosT = ws;
    float* sinT = ws + 8192;
    float* Q    = ws + 16384;
    float* Kv   = Q + SZ;
    float* Vv   = Kv + SZ;
    float* AO   = Vv + SZ;     // attention output in [B,T,C]

    hipLaunchKernelGGL(rope_table_k, dim3(32), dim3(256), 0, stream, cosT, sinT);

    dim3 g1(N3C / BN, (Bb * Tt) / BM);  // (9, 128)
    hipLaunchKernelGGL((gemm_k<true>), g1, dim3(256), 0, stream,
                       x, w_attn, Bb * Tt, N3C, Cc,
                       cosT, sinT, Q, Kv, Vv, (float*)nullptr);

    hipLaunchKernelGGL(attn_k, dim3(Bb * NHh * 8), dim3(64), 0, stream,
                       Q, Kv, Vv, AO);

    dim3 g2(Cc / BN, (Bb * Tt) / BM);   // (3, 128)
    hipLaunchKernelGGL((gemm_k<false>), g2, dim3(256), 0, stream,
                       AO, w_proj, Bb * Tt, Cc, Cc,
                       (const float*)nullptr, (const float*)nullptr,
                       (float*)nullptr, (float*)nullptr, (float*)nullptr, out);
}

// Round 3
// 327.737 us; speedup vs baseline: 1.9449x; 1.5920x over previous
//
#include <hip/hip_runtime.h>
#include <math.h>

#define Bb  64
#define Tt  256
#define Cc  384
#define NHh 6
#define HDd 64
#define N3C 1152
#define Mm  16384

typedef __attribute__((ext_vector_type(8))) short bf16x8;
typedef __attribute__((ext_vector_type(4))) float f32x4;

__device__ __forceinline__ ushort f2bf(float f) {
    uint u = __float_as_uint(f);
    u += 0x7fff + ((u >> 16) & 1);          // RNE
    return (ushort)(u >> 16);
}
__device__ __forceinline__ float bf2f(ushort h) {
    return __uint_as_float(((uint)h) << 16);
}

// ---------------- RoPE table: cos/sin[t][i], t<256, i<32 ----------------
__global__ void rope_table_k(float* __restrict__ cosT, float* __restrict__ sinT) {
    int idx = blockIdx.x * 256 + threadIdx.x;   // 8192 total
    int t = idx >> 5;
    int i = idx & 31;
    float inv = powf(10000.0f, -(float)i / 32.0f);
    float ang = (float)t * inv;
    cosT[idx] = cosf(ang);
    sinT[idx] = sinf(ang);
}

// ---------------- x -> bf16 hi/lo split ----------------
__global__ __launch_bounds__(256)
void cvt_x_k(const float* __restrict__ x, ushort* __restrict__ Xh,
             ushort* __restrict__ Xl) {
    int i = (blockIdx.x * 256 + threadIdx.x) * 4;
    float4 v = *(const float4*)&x[i];
    float vv[4] = {v.x, v.y, v.z, v.w};
    ushort h[4], l[4];
#pragma unroll
    for (int j = 0; j < 4; ++j) {
        h[j] = f2bf(vv[j]);
        l[j] = f2bf(vv[j] - bf2f(h[j]));
    }
    *(uint2*)&Xh[i] = *(uint2*)h;
    *(uint2*)&Xl[i] = *(uint2*)l;
}

// ---------------- weight transpose + hi/lo split: w[K][N] -> Wt[N][K] ----
__global__ __launch_bounds__(256)
void cvt_w_k(const float* __restrict__ w, ushort* __restrict__ Wth,
             ushort* __restrict__ Wtl, int N, int K) {
    int nl = threadIdx.x & 63, kb = threadIdx.x >> 6;
    int n  = blockIdx.x * 64 + nl;
    int k0 = blockIdx.y * 64 + kb * 16;
    ushort h[16], l[16];
#pragma unroll
    for (int j = 0; j < 16; ++j) {
        float v = w[(size_t)(k0 + j) * N + n];   // coalesced across lanes
        h[j] = f2bf(v);
        l[j] = f2bf(v - bf2f(h[j]));
    }
    size_t o = (size_t)n * K + k0;
    *(uint4*)&Wth[o]     = *(uint4*)&h[0];
    *(uint4*)&Wth[o + 8] = *(uint4*)&h[8];
    *(uint4*)&Wtl[o]     = *(uint4*)&l[0];
    *(uint4*)&Wtl[o + 8] = *(uint4*)&l[8];
}

// ---------------- split-bf16 MFMA GEMM: C = A[M x K] * B[K x N] ----------
// A given as hi/lo bf16 [M][K]; B given TRANSPOSED hi/lo bf16 [N][K].
// 128x128 tile, 4 waves (2x2), BK=32, mfma_f32_16x16x32_bf16, 3-mfma split.
#define PRK 40   // padded LDS row stride in bf16 (80 B) -> 2-way banks (free)

template<bool ROPE>
__global__ __launch_bounds__(256)
void mfma_gemm_k(const ushort* __restrict__ Ah, const ushort* __restrict__ Al,
                 const ushort* __restrict__ Bth, const ushort* __restrict__ Btl,
                 int N, int K,
                 const float* __restrict__ cosT, const float* __restrict__ sinT,
                 float* __restrict__ outQ, float* __restrict__ outK2,
                 float* __restrict__ outV, float* __restrict__ outC)
{
    __shared__ ushort sAh[128*PRK], sAl[128*PRK], sBh[128*PRK], sBl[128*PRK];
    const int tid  = threadIdx.x;
    const int lane = tid & 63;
    const int wid  = tid >> 6;
    const int wm   = wid >> 1, wn = wid & 1;
    const int m0   = blockIdx.y * 128, n0 = blockIdx.x * 128;

    const int srow = tid >> 1;           // 0..127
    const int sseg = (tid & 1) * 2;      // 16B segment pair {0,1} or {2,3}

    f32x4 acc[4][4];
#pragma unroll
    for (int i = 0; i < 4; ++i)
#pragma unroll
        for (int j = 0; j < 4; ++j) acc[i][j] = (f32x4){0.f, 0.f, 0.f, 0.f};

    const size_t aoff = (size_t)(m0 + srow) * K;
    const size_t boff = (size_t)(n0 + srow) * K;

    for (int kc = 0; kc < K; kc += 32) {
        const int ge = kc + sseg * 8;
        uint4 ah0 = *(const uint4*)&Ah [aoff + ge];
        uint4 ah1 = *(const uint4*)&Ah [aoff + ge + 8];
        uint4 al0 = *(const uint4*)&Al [aoff + ge];
        uint4 al1 = *(const uint4*)&Al [aoff + ge + 8];
        uint4 bh0 = *(const uint4*)&Bth[boff + ge];
        uint4 bh1 = *(const uint4*)&Bth[boff + ge + 8];
        uint4 bl0 = *(const uint4*)&Btl[boff + ge];
        uint4 bl1 = *(const uint4*)&Btl[boff + ge + 8];
        __syncthreads();                 // prev tile fully consumed
        const int le = srow * PRK + sseg * 8;
        *(uint4*)&sAh[le]     = ah0;
        *(uint4*)&sAh[le + 8] = ah1;
        *(uint4*)&sAl[le]     = al0;
        *(uint4*)&sAl[le + 8] = al1;
        *(uint4*)&sBh[le]     = bh0;
        *(uint4*)&sBh[le + 8] = bh1;
        *(uint4*)&sBl[le]     = bl0;
        *(uint4*)&sBl[le + 8] = bl1;
        __syncthreads();

        const int kslot = (lane >> 4) * 8;
        const int rA = wm * 64 + (lane & 15);
        const int rB = wn * 64 + (lane & 15);
        bf16x8 fa_h[4], fa_l[4], fb_h[4], fb_l[4];
#pragma unroll
        for (int f = 0; f < 4; ++f) {
            fa_h[f] = *(const bf16x8*)&sAh[(rA + f*16)*PRK + kslot];
            fa_l[f] = *(const bf16x8*)&sAl[(rA + f*16)*PRK + kslot];
            fb_h[f] = *(const bf16x8*)&sBh[(rB + f*16)*PRK + kslot];
            fb_l[f] = *(const bf16x8*)&sBl[(rB + f*16)*PRK + kslot];
        }
#pragma unroll
        for (int fm = 0; fm < 4; ++fm)
#pragma unroll
            for (int fn = 0; fn < 4; ++fn) {
                acc[fm][fn] = __builtin_amdgcn_mfma_f32_16x16x32_bf16(
                                  fa_h[fm], fb_h[fn], acc[fm][fn], 0, 0, 0);
                acc[fm][fn] = __builtin_amdgcn_mfma_f32_16x16x32_bf16(
                                  fa_h[fm], fb_l[fn], acc[fm][fn], 0, 0, 0);
                acc[fm][fn] = __builtin_amdgcn_mfma_f32_16x16x32_bf16(
                                  fa_l[fm], fb_h[fn], acc[fm][fn], 0, 0, 0);
            }
    }

    // ---- epilogue: C frag mapping row = 4*(lane>>4)+r, col = lane&15 ----
    if (ROPE) {
#pragma unroll
        for (int fn = 0; fn < 4; ++fn) {
            int nglob = n0 + wn*64 + fn*16 + (lane & 15);
            int which = nglob / Cc;                 // 0=q 1=k 2=v (uniform)
            int nloc  = nglob - which * Cc;
            int h = nloc >> 6, d = nloc & 63;
            float* dst = which == 0 ? outQ : (which == 1 ? outK2 : outV);
#pragma unroll
            for (int fm = 0; fm < 4; ++fm) {
#pragma unroll
                for (int r = 0; r < 4; ++r) {
                    int m = m0 + wm*64 + fm*16 + ((lane >> 4) << 2) + r;
                    int b = m >> 8, t = m & 255;
                    float v = acc[fm][fn][r];
                    float part = __shfl_xor(v, 1);  // RoPE partner (d^1)
                    float cs = cosT[t*32 + (d >> 1)];
                    float sn = sinT[t*32 + (d >> 1)];
                    float nv;
                    if (which == 2) {
                        nv = v;
                    } else {
                        nv = (d & 1) ? fmaf(v, cs,  part * sn)
                                     : fmaf(v, cs, -part * sn);
                        if (which == 0) nv *= 0.125f;   // hd^-0.5
                    }
                    dst[((size_t)(b*NHh + h)*Tt + t)*HDd + d] = nv;
                }
            }
        }
    } else {
#pragma unroll
        for (int fm = 0; fm < 4; ++fm)
#pragma unroll
            for (int fn = 0; fn < 4; ++fn) {
                int nglob = n0 + wn*64 + fn*16 + (lane & 15);
#pragma unroll
                for (int r = 0; r < 4; ++r) {
                    int m = m0 + wm*64 + fm*16 + ((lane >> 4) << 2) + r;
                    outC[(size_t)m * N + nglob] = acc[fm][fn][r];
                }
            }
    }
}

// ---------------- Flash attention, fp32, causal, BALANCED ----------------
// 16-row slabs, 4 lanes per row (16 dims each). Block = (bh, pair i):
// phase 0 does slab i (i+1 chunks), phase 1 slab 15-i (16-i chunks):
// uniform 17 chunks/block. Dbuf global_load_lds + counted vmcnt, no barriers.
#define ACH 16

__device__ __forceinline__ void gll16(const float* g, float* l) {
    __builtin_amdgcn_global_load_lds(
        (const __attribute__((address_space(1))) void*)g,
        (__attribute__((address_space(3))) void*)l, 16, 0, 0);
}

__global__ __launch_bounds__(64)
void attn_k(const float* __restrict__ Q, const float* __restrict__ Kv,
            const float* __restrict__ Vv,
            ushort* __restrict__ AOh, ushort* __restrict__ AOl)
{
    __shared__ float sKV[2][2][ACH * HDd];   // 16 KB
    const int pr   = blockIdx.x & 7;
    const int bh   = blockIdx.x >> 3;
    const int lane = threadIdx.x;
    const int ro   = lane >> 2;              // row in slab (0..15)
    const int qu   = lane & 3;               // dim quarter

    const float* kbase = Kv + (size_t)bh * Tt * HDd;
    const float* vbase = Vv + (size_t)bh * Tt * HDd;

#define STAGE(ch, buf)                                                    \
    {                                                                     \
        const float* kg_ = kbase + (ch) * ACH * HDd;                      \
        const float* vg_ = vbase + (ch) * ACH * HDd;                      \
        float* kl_ = &sKV[(buf)][0][0];                                   \
        float* vl_ = &sKV[(buf)][1][0];                                   \
        _Pragma("unroll")                                                 \
        for (int jj = 0; jj < 4; ++jj) {                                  \
            gll16(kg_ + jj * 256 + lane * 4, kl_ + jj * 256);             \
            gll16(vg_ + jj * 256 + lane * 4, vl_ + jj * 256);             \
        }                                                                 \
    }

    STAGE(0, 0)
    int gidx = 0;

    for (int p = 0; p < 2; ++p) {
        const int sl  = p ? (15 - pr) : pr;
        const int row = sl * 16 + ro;
        const int nch = sl + 1;

        float q[16];
        {
            const float* qr = Q + (size_t)(bh * Tt + row) * HDd + qu * 16;
#pragma unroll
            for (int j = 0; j < 4; ++j)
                *(float4*)&q[j*4] = *(const float4*)&qr[j*4];
        }
        float o[16];
#pragma unroll
        for (int j = 0; j < 16; ++j) o[j] = 0.f;
        float mx = -1e30f, lsum = 0.f;

        for (int c = 0; c < nch; ++c) {
            const int buf = gidx & 1;
            const bool lastall = (p == 1) && (c == nch - 1);
            if (c + 1 < nch)  STAGE(c + 1, (gidx + 1) & 1)
            else if (p == 0)  STAGE(0,     (gidx + 1) & 1)
            if (!lastall) asm volatile("s_waitcnt vmcnt(8)" ::: "memory");
            else          asm volatile("s_waitcnt vmcnt(0)" ::: "memory");
            __builtin_amdgcn_sched_barrier(0);
            const float* Kc = &sKV[buf][0][0];
            const float* Vc = &sKV[buf][1][0];

            float s[ACH];
#pragma unroll
            for (int kk = 0; kk < ACH; ++kk) {
                const float* kr = Kc + kk * HDd + qu * 16;
                float4 k0 = *(const float4*)&kr[0];
                float4 k1 = *(const float4*)&kr[4];
                float4 k2 = *(const float4*)&kr[8];
                float4 k3 = *(const float4*)&kr[12];
                float a0 = q[0] * k0.x;
                a0 = fmaf(q[1],  k0.y, a0); a0 = fmaf(q[2],  k0.z, a0);
                a0 = fmaf(q[3],  k0.w, a0);
                float a1 = q[4] * k1.x;
                a1 = fmaf(q[5],  k1.y, a1); a1 = fmaf(q[6],  k1.z, a1);
                a1 = fmaf(q[7],  k1.w, a1);
                float a2 = q[8] * k2.x;
                a2 = fmaf(q[9],  k2.y, a2); a2 = fmaf(q[10], k2.z, a2);
                a2 = fmaf(q[11], k2.w, a2);
                float a3 = q[12] * k3.x;
                a3 = fmaf(q[13], k3.y, a3); a3 = fmaf(q[14], k3.z, a3);
                a3 = fmaf(q[15], k3.w, a3);
                float acc = (a0 + a1) + (a2 + a3);
                acc += __shfl_xor(acc, 1);
                acc += __shfl_xor(acc, 2);
                s[kk] = (c * ACH + kk <= row) ? acc : -1e30f;
            }

            float pm = s[0];
#pragma unroll
            for (int kk = 1; kk < ACH; ++kk) pm = fmaxf(pm, s[kk]);
            float nm   = fmaxf(mx, pm);
            float resc = __expf(mx - nm);
            lsum *= resc;
#pragma unroll
            for (int j = 0; j < 16; ++j) o[j] *= resc;

#pragma unroll
            for (int kk = 0; kk < ACH; ++kk) {
                float pp = __expf(s[kk] - nm);
                lsum += pp;
                const float* vr = Vc + kk * HDd + qu * 16;
#pragma unroll
                for (int j = 0; j < 4; ++j) {
                    float4 vv = *(const float4*)&vr[j*4];
                    o[j*4+0] = fmaf(pp, vv.x, o[j*4+0]);
                    o[j*4+1] = fmaf(pp, vv.y, o[j*4+1]);
                    o[j*4+2] = fmaf(pp, vv.z, o[j*4+2]);
                    o[j*4+3] = fmaf(pp, vv.w, o[j*4+3]);
                }
            }
            mx = nm;
            ++gidx;
        }

        // epilogue: write AO as bf16 hi/lo (feeds proj GEMM)
        float inv = 1.0f / lsum;
        int b = bh / NHh, hh2 = bh % NHh;
        size_t base = ((size_t)(b * Tt + row)) * Cc + hh2 * HDd + qu * 16;
        ushort h16[16], l16[16];
#pragma unroll
        for (int j = 0; j < 16; ++j) {
            float v = o[j] * inv;
            h16[j] = f2bf(v);
            l16[j] = f2bf(v - bf2f(h16[j]));
        }
        *(uint4*)&AOh[base]     = *(uint4*)&h16[0];
        *(uint4*)&AOh[base + 8] = *(uint4*)&h16[8];
        *(uint4*)&AOl[base]     = *(uint4*)&l16[0];
        *(uint4*)&AOl[base + 8] = *(uint4*)&l16[8];
    }
#undef STAGE
}

// ---------------- launcher ----------------
extern "C" void kernel_launch(void* const* d_in, const int* in_sizes, int n_in,
                              void* d_out, int out_size, void* d_ws, size_t ws_size,
                              hipStream_t stream) {
    (void)in_sizes; (void)n_in; (void)out_size; (void)ws_size;
    const float* x      = (const float*)d_in[0];
    const float* w_attn = (const float*)d_in[1];
    const float* w_proj = (const float*)d_in[2];
    float* out = (float*)d_out;

    const size_t SZ = (size_t)Bb * NHh * Tt * HDd;   // 6,291,456
    char* base = (char*)d_ws;
    float*  cosT = (float*)base;
    float*  sinT = cosT + 8192;
    float*  Q    = (float*)(base + 65536);
    float*  Kv   = Q  + SZ;
    float*  Vv   = Kv + SZ;
    ushort* Xh   = (ushort*)(Vv + SZ);
    ushort* Xl   = Xh + SZ;
    ushort* AOh  = Xh;                // alias: X dead after QKV GEMM
    ushort* AOl  = Xl;
    ushort* Wath = Xl + SZ;
    ushort* Watl = Wath + (size_t)N3C * Cc;
    ushort* Wph  = Watl + (size_t)N3C * Cc;
    ushort* Wpl  = Wph  + (size_t)Cc * Cc;

    hipLaunchKernelGGL(rope_table_k, dim3(32), dim3(256), 0, stream, cosT, sinT);
    hipLaunchKernelGGL(cvt_x_k, dim3(Mm * Cc / 1024), dim3(256), 0, stream,
                       x, Xh, Xl);
    hipLaunchKernelGGL(cvt_w_k, dim3(N3C / 64, Cc / 64), dim3(256), 0, stream,
                       w_attn, Wath, Watl, N3C, Cc);
    hipLaunchKernelGGL(cvt_w_k, dim3(Cc / 64, Cc / 64), dim3(256), 0, stream,
                       w_proj, Wph, Wpl, Cc, Cc);

    hipLaunchKernelGGL((mfma_gemm_k<true>), dim3(N3C / 128, Mm / 128), dim3(256),
                       0, stream, Xh, Xl, Wath, Watl, N3C, Cc,
                       cosT, sinT, Q, Kv, Vv, (float*)nullptr);

    hipLaunchKernelGGL(attn_k, dim3(Bb * NHh * 8), dim3(64), 0, stream,
                       Q, Kv, Vv, AOh, AOl);

    hipLaunchKernelGGL((mfma_gemm_k<false>), dim3(Cc / 128, Mm / 128), dim3(256),
                       0, stream, AOh, AOl, Wph, Wpl, Cc, Cc,
                       (const float*)nullptr, (const float*)nullptr,
                       (float*)nullptr, (float*)nullptr, (float*)nullptr, out);
}

// Round 4
// 259.106 us; speedup vs baseline: 2.4601x; 1.2649x over previous
//
#include <hip/hip_runtime.h>
#include <math.h>

#define Bb  64
#define Tt  256
#define Cc  384
#define NHh 6
#define HDd 64
#define N3C 1152
#define Mm  16384

typedef __attribute__((ext_vector_type(8))) short bf16x8;
typedef __attribute__((ext_vector_type(4))) float f32x4;

#define MFMA16(a, b, c) __builtin_amdgcn_mfma_f32_16x16x32_bf16((a), (b), (c), 0, 0, 0)

__device__ __forceinline__ ushort f2bf(float f) {
    uint u = __float_as_uint(f);
    u += 0x7fff + ((u >> 16) & 1);          // RNE
    return (ushort)(u >> 16);
}
__device__ __forceinline__ float bf2f(ushort h) {
    return __uint_as_float(((uint)h) << 16);
}
__device__ __forceinline__ uint cvtpk(float lo, float hi) {
    uint r;
    asm("v_cvt_pk_bf16_f32 %0, %1, %2" : "=v"(r) : "v"(lo), "v"(hi));
    return r;
}

// ---------------- RoPE table ----------------
__global__ void rope_table_k(float* __restrict__ cosT, float* __restrict__ sinT) {
    int idx = blockIdx.x * 256 + threadIdx.x;   // 8192 total
    int t = idx >> 5;
    int i = idx & 31;
    float inv = powf(10000.0f, -(float)i / 32.0f);
    float ang = (float)t * inv;
    cosT[idx] = cosf(ang);
    sinT[idx] = sinf(ang);
}

// ---------------- x -> bf16 hi/lo split ----------------
__global__ __launch_bounds__(256)
void cvt_x_k(const float* __restrict__ x, ushort* __restrict__ Xh,
             ushort* __restrict__ Xl) {
    int i = (blockIdx.x * 256 + threadIdx.x) * 4;
    float4 v = *(const float4*)&x[i];
    float vv[4] = {v.x, v.y, v.z, v.w};
    ushort h[4], l[4];
#pragma unroll
    for (int j = 0; j < 4; ++j) {
        h[j] = f2bf(vv[j]);
        l[j] = f2bf(vv[j] - bf2f(h[j]));
    }
    *(uint2*)&Xh[i] = *(uint2*)h;
    *(uint2*)&Xl[i] = *(uint2*)l;
}

// ---------------- weight transpose + hi/lo split ----------------
__global__ __launch_bounds__(256)
void cvt_w_k(const float* __restrict__ w, ushort* __restrict__ Wth,
             ushort* __restrict__ Wtl, int N, int K) {
    int nl = threadIdx.x & 63, kb = threadIdx.x >> 6;
    int n  = blockIdx.x * 64 + nl;
    int k0 = blockIdx.y * 64 + kb * 16;
    ushort h[16], l[16];
#pragma unroll
    for (int j = 0; j < 16; ++j) {
        float v = w[(size_t)(k0 + j) * N + n];
        h[j] = f2bf(v);
        l[j] = f2bf(v - bf2f(h[j]));
    }
    size_t o = (size_t)n * K + k0;
    *(uint4*)&Wth[o]     = *(uint4*)&h[0];
    *(uint4*)&Wth[o + 8] = *(uint4*)&h[8];
    *(uint4*)&Wtl[o]     = *(uint4*)&l[0];
    *(uint4*)&Wtl[o + 8] = *(uint4*)&l[8];
}

// ---------------- split-bf16 MFMA GEMM ----------------
// ROPE=true epilogue: RoPE+scale, emit Qh/Ql,Kh/Kl [bh][T][64] and
// Vth/Vtl TRANSPOSED [bh][64][T]. ROPE=false: fp32 store to outC.
#define PRK 40

template<bool ROPE>
__global__ __launch_bounds__(256)
void mfma_gemm_k(const ushort* __restrict__ Ah, const ushort* __restrict__ Al,
                 const ushort* __restrict__ Bth, const ushort* __restrict__ Btl,
                 int N, int K,
                 const float* __restrict__ cosT, const float* __restrict__ sinT,
                 ushort* __restrict__ Qh, ushort* __restrict__ Ql,
                 ushort* __restrict__ Kh, ushort* __restrict__ Kl,
                 ushort* __restrict__ Vth, ushort* __restrict__ Vtl,
                 float* __restrict__ outC)
{
    __shared__ ushort sAh[128*PRK], sAl[128*PRK], sBh[128*PRK], sBl[128*PRK];
    const int tid  = threadIdx.x;
    const int lane = tid & 63;
    const int wid  = tid >> 6;
    const int wm   = wid >> 1, wn = wid & 1;
    const int m0   = blockIdx.y * 128, n0 = blockIdx.x * 128;

    const int srow = tid >> 1;
    const int sseg = (tid & 1) * 2;

    f32x4 acc[4][4];
#pragma unroll
    for (int i = 0; i < 4; ++i)
#pragma unroll
        for (int j = 0; j < 4; ++j) acc[i][j] = (f32x4){0.f, 0.f, 0.f, 0.f};

    const size_t aoff = (size_t)(m0 + srow) * K;
    const size_t boff = (size_t)(n0 + srow) * K;

    for (int kc = 0; kc < K; kc += 32) {
        const int ge = kc + sseg * 8;
        uint4 ah0 = *(const uint4*)&Ah [aoff + ge];
        uint4 ah1 = *(const uint4*)&Ah [aoff + ge + 8];
        uint4 al0 = *(const uint4*)&Al [aoff + ge];
        uint4 al1 = *(const uint4*)&Al [aoff + ge + 8];
        uint4 bh0 = *(const uint4*)&Bth[boff + ge];
        uint4 bh1 = *(const uint4*)&Bth[boff + ge + 8];
        uint4 bl0 = *(const uint4*)&Btl[boff + ge];
        uint4 bl1 = *(const uint4*)&Btl[boff + ge + 8];
        __syncthreads();
        const int le = srow * PRK + sseg * 8;
        *(uint4*)&sAh[le]     = ah0;
        *(uint4*)&sAh[le + 8] = ah1;
        *(uint4*)&sAl[le]     = al0;
        *(uint4*)&sAl[le + 8] = al1;
        *(uint4*)&sBh[le]     = bh0;
        *(uint4*)&sBh[le + 8] = bh1;
        *(uint4*)&sBl[le]     = bl0;
        *(uint4*)&sBl[le + 8] = bl1;
        __syncthreads();

        const int kslot = (lane >> 4) * 8;
        const int rA = wm * 64 + (lane & 15);
        const int rB = wn * 64 + (lane & 15);
        bf16x8 fa_h[4], fa_l[4], fb_h[4], fb_l[4];
#pragma unroll
        for (int f = 0; f < 4; ++f) {
            fa_h[f] = *(const bf16x8*)&sAh[(rA + f*16)*PRK + kslot];
            fa_l[f] = *(const bf16x8*)&sAl[(rA + f*16)*PRK + kslot];
            fb_h[f] = *(const bf16x8*)&sBh[(rB + f*16)*PRK + kslot];
            fb_l[f] = *(const bf16x8*)&sBl[(rB + f*16)*PRK + kslot];
        }
#pragma unroll
        for (int fm = 0; fm < 4; ++fm)
#pragma unroll
            for (int fn = 0; fn < 4; ++fn) {
                acc[fm][fn] = MFMA16(fa_h[fm], fb_h[fn], acc[fm][fn]);
                acc[fm][fn] = MFMA16(fa_h[fm], fb_l[fn], acc[fm][fn]);
                acc[fm][fn] = MFMA16(fa_l[fm], fb_h[fn], acc[fm][fn]);
            }
    }

    if (ROPE) {
#pragma unroll
        for (int fn = 0; fn < 4; ++fn) {
            int nglob = n0 + wn*64 + fn*16 + (lane & 15);
            int which = nglob / Cc;                 // wave-uniform
            int nloc  = nglob - which * Cc;
            int h = nloc >> 6, d = nloc & 63;
#pragma unroll
            for (int fm = 0; fm < 4; ++fm) {
                int mbase = m0 + wm*64 + fm*16 + ((lane >> 4) << 2);
                int b = mbase >> 8, t0 = mbase & 255;
                int bh = b * NHh + h;
                if (which == 2) {
                    ushort hv[4], lv[4];
#pragma unroll
                    for (int r = 0; r < 4; ++r) {
                        float v = acc[fm][fn][r];
                        hv[r] = f2bf(v);
                        lv[r] = f2bf(v - bf2f(hv[r]));
                    }
                    size_t o = ((size_t)bh * HDd + d) * Tt + t0;
                    *(uint2*)&Vth[o] = *(uint2*)hv;
                    *(uint2*)&Vtl[o] = *(uint2*)lv;
                } else {
#pragma unroll
                    for (int r = 0; r < 4; ++r) {
                        int t = t0 + r;
                        float v = acc[fm][fn][r];
                        float part = __shfl_xor(v, 1);
                        float cs = cosT[t*32 + (d >> 1)];
                        float sn = sinT[t*32 + (d >> 1)];
                        float nv = (d & 1) ? fmaf(v, cs,  part * sn)
                                           : fmaf(v, cs, -part * sn);
                        if (which == 0) nv *= 0.125f;
                        ushort hv = f2bf(nv);
                        ushort lv = f2bf(nv - bf2f(hv));
                        size_t o = ((size_t)bh * Tt + t) * HDd + d;
                        if (which == 0) { Qh[o] = hv; Ql[o] = lv; }
                        else            { Kh[o] = hv; Kl[o] = lv; }
                    }
                }
            }
        }
    } else {
#pragma unroll
        for (int fm = 0; fm < 4; ++fm)
#pragma unroll
            for (int fn = 0; fn < 4; ++fn) {
                int nglob = n0 + wn*64 + fn*16 + (lane & 15);
#pragma unroll
                for (int r = 0; r < 4; ++r) {
                    int m = m0 + wm*64 + fm*16 + ((lane >> 4) << 2) + r;
                    outC[(size_t)m * N + nglob] = acc[fm][fn][r];
                }
            }
    }
}

// ---------------- MFMA flash attention, causal, split-bf16 ----------------
// Block = (b,h,parity e): 4 waves, each handles q-tiles {e+2w, e+14-2w}
// (uniform 9 chunk-units). Swapped QK^T -> D[key][q]; P transposed to
// A-frag layout via per-wave XOR-swizzled LDS (1KB); PV from transposed V.
__global__ __launch_bounds__(256, 3)
void attn_mfma_k(const ushort* __restrict__ Qh, const ushort* __restrict__ Ql,
                 const ushort* __restrict__ Kh, const ushort* __restrict__ Kl,
                 const ushort* __restrict__ Vth, const ushort* __restrict__ Vtl,
                 ushort* __restrict__ AOh, ushort* __restrict__ AOl)
{
    __shared__ ushort sP[4][2][512];        // [wave][hi/lo][16q x 32key] = 8KB
    const int e    = blockIdx.x & 1;
    const int bh   = blockIdx.x >> 1;
    const int wid  = threadIdx.x >> 6;
    const int lane = threadIdx.x & 63;
    const int q16  = lane & 15;             // col (q) / A-row (key) / B-col (dim)
    const int g    = lane >> 4;

    const int b = bh / NHh, h = bh % NHh;
    char* pbh = (char*)&sP[wid][0][0];
    char* pbl = (char*)&sP[wid][1][0];
    const int xorq = (q16 & 3) << 4;

    const size_t qkbase = (size_t)bh * Tt * HDd;
    const size_t vtbase = (size_t)bh * HDd * Tt;

#pragma unroll
    for (int ti = 0; ti < 2; ++ti) {
        const int tile  = ti == 0 ? (e + 2*wid) : (e + 14 - 2*wid);
        const int qbase = tile * 16;
        const int nch   = (tile >> 1) + 1;

        // Q B-fragments (hi/lo x 2 k-steps), held in registers
        bf16x8 fqh[2], fql[2];
        {
            const size_t qo = qkbase + (size_t)(qbase + q16) * HDd + 8*g;
            fqh[0] = *(const bf16x8*)&Qh[qo];
            fqh[1] = *(const bf16x8*)&Qh[qo + 32];
            fql[0] = *(const bf16x8*)&Ql[qo];
            fql[1] = *(const bf16x8*)&Ql[qo + 32];
        }
        f32x4 acc[4];
#pragma unroll
        for (int dt = 0; dt < 4; ++dt) acc[dt] = (f32x4){0.f, 0.f, 0.f, 0.f};
        float mx = -1e30f, lsum = 0.f;

        for (int c = 0; c < nch; ++c) {
            const int kb = c * 32;
            // ---- QK^T (swapped): D[key][q], split 3-mfma over hi/lo ----
            f32x4 S[2];
#pragma unroll
            for (int kt = 0; kt < 2; ++kt) {
                const size_t ko = qkbase + (size_t)(kb + 16*kt + q16) * HDd + 8*g;
                bf16x8 kh0 = *(const bf16x8*)&Kh[ko];
                bf16x8 kh1 = *(const bf16x8*)&Kh[ko + 32];
                bf16x8 kl0 = *(const bf16x8*)&Kl[ko];
                bf16x8 kl1 = *(const bf16x8*)&Kl[ko + 32];
                f32x4 s = (f32x4){0.f, 0.f, 0.f, 0.f};
                s = MFMA16(kh0, fqh[0], s);
                s = MFMA16(kh0, fql[0], s);
                s = MFMA16(kl0, fqh[0], s);
                s = MFMA16(kh1, fqh[1], s);
                s = MFMA16(kh1, fql[1], s);
                s = MFMA16(kl1, fqh[1], s);
                S[kt] = s;
            }
            // ---- causal mask ----
            const int q = qbase + q16;
#pragma unroll
            for (int kt = 0; kt < 2; ++kt)
#pragma unroll
                for (int r = 0; r < 4; ++r) {
                    int key = kb + 16*kt + 4*g + r;
                    S[kt][r] = (key <= q) ? S[kt][r] : -1e30f;
                }
            // ---- online softmax (reduce over keys: 8 regs + xor16 + xor32) --
            float pm = fmaxf(fmaxf(fmaxf(S[0][0], S[0][1]), fmaxf(S[0][2], S[0][3])),
                             fmaxf(fmaxf(S[1][0], S[1][1]), fmaxf(S[1][2], S[1][3])));
            pm = fmaxf(pm, __shfl_xor(pm, 16));
            pm = fmaxf(pm, __shfl_xor(pm, 32));
            float nm   = fmaxf(mx, pm);
            float resc = __expf(mx - nm);
            mx = nm;

            float p[2][4];
            float csum = 0.f;
#pragma unroll
            for (int kt = 0; kt < 2; ++kt)
#pragma unroll
                for (int r = 0; r < 4; ++r) {
                    p[kt][r] = __expf(S[kt][r] - nm);
                    csum += p[kt][r];
                }
            csum += __shfl_xor(csum, 16);
            csum += __shfl_xor(csum, 32);
            lsum = lsum * resc + csum;

            // rescale O (rows q=qbase+4g+r need resc of col q -> shfl)
            float rs[4];
#pragma unroll
            for (int r = 0; r < 4; ++r) rs[r] = __shfl(resc, 4*g + r);
#pragma unroll
            for (int dt = 0; dt < 4; ++dt)
#pragma unroll
                for (int r = 0; r < 4; ++r) acc[dt][r] *= rs[r];

            // ---- P -> LDS (bf16 hi/lo, transposed to A-frag layout) ----
#pragma unroll
            for (int kt = 0; kt < 2; ++kt) {
                uint a0 = cvtpk(p[kt][0], p[kt][1]);
                uint a1 = cvtpk(p[kt][2], p[kt][3]);
                float e0 = p[kt][0] - __uint_as_float(a0 << 16);
                float e1 = p[kt][1] - __uint_as_float(a0 & 0xffff0000u);
                float e2 = p[kt][2] - __uint_as_float(a1 << 16);
                float e3 = p[kt][3] - __uint_as_float(a1 & 0xffff0000u);
                uint b0 = cvtpk(e0, e1);
                uint b1 = cvtpk(e2, e3);
                int off = q16 * 64 + ((32*kt + 8*g) ^ xorq);
                *(uint2*)(pbh + off) = (uint2){a0, a1};
                *(uint2*)(pbl + off) = (uint2){b0, b1};
            }
            // A-frag read (same wave; DS ops are in-order, no barrier needed)
            const int roff = q16 * 64 + ((16*g) ^ xorq);
            bf16x8 pah = *(const bf16x8*)(pbh + roff);
            bf16x8 pal = *(const bf16x8*)(pbl + roff);

            // ---- PV: A=P[16q x 32key], B=Vt[dim][key], 3-mfma split ----
#pragma unroll
            for (int dt = 0; dt < 4; ++dt) {
                const size_t vo = vtbase + (size_t)(16*dt + q16) * Tt + kb + 8*g;
                bf16x8 vh = *(const bf16x8*)&Vth[vo];
                bf16x8 vl = *(const bf16x8*)&Vtl[vo];
                acc[dt] = MFMA16(pah, vh, acc[dt]);
                acc[dt] = MFMA16(pah, vl, acc[dt]);
                acc[dt] = MFMA16(pal, vh, acc[dt]);
            }
        }

        // ---- epilogue: O /= lsum, write bf16 hi/lo to AO [B,T,C] ----
        float il[4];
#pragma unroll
        for (int r = 0; r < 4; ++r) il[r] = 1.0f / __shfl(lsum, 4*g + r);
#pragma unroll
        for (int dt = 0; dt < 4; ++dt) {
            int d = 16*dt + q16;
#pragma unroll
            for (int r = 0; r < 4; ++r) {
                int q = qbase + 4*g + r;
                float o = acc[dt][r] * il[r];
                ushort oh = f2bf(o);
                ushort ol = f2bf(o - bf2f(oh));
                size_t oo = ((size_t)(b * Tt + q)) * Cc + h * HDd + d;
                AOh[oo] = oh;
                AOl[oo] = ol;
            }
        }
    }
}

// ---------------- launcher ----------------
extern "C" void kernel_launch(void* const* d_in, const int* in_sizes, int n_in,
                              void* d_out, int out_size, void* d_ws, size_t ws_size,
                              hipStream_t stream) {
    (void)in_sizes; (void)n_in; (void)out_size; (void)ws_size;
    const float* x      = (const float*)d_in[0];
    const float* w_attn = (const float*)d_in[1];
    const float* w_proj = (const float*)d_in[2];
    float* out = (float*)d_out;

    const size_t SZ = (size_t)Bb * NHh * Tt * HDd;   // 6,291,456
    char* base = (char*)d_ws;
    float*  cosT = (float*)base;
    float*  sinT = cosT + 8192;
    ushort* Qh   = (ushort*)(base + 65536);
    ushort* Ql   = Qh + SZ;
    ushort* Kh   = Ql + SZ;
    ushort* Kl   = Kh + SZ;
    ushort* Vth  = Kl + SZ;
    ushort* Vtl  = Vth + SZ;
    ushort* Xh   = Vtl + SZ;
    ushort* Xl   = Xh + SZ;
    ushort* AOh  = Xh;                // alias: X dead after QKV GEMM
    ushort* AOl  = Xl;
    ushort* Wath = Xl + SZ;
    ushort* Watl = Wath + (size_t)N3C * Cc;
    ushort* Wph  = Watl + (size_t)N3C * Cc;
    ushort* Wpl  = Wph  + (size_t)Cc * Cc;

    hipLaunchKernelGGL(rope_table_k, dim3(32), dim3(256), 0, stream, cosT, sinT);
    hipLaunchKernelGGL(cvt_x_k, dim3(Mm * Cc / 1024), dim3(256), 0, stream,
                       x, Xh, Xl);
    hipLaunchKernelGGL(cvt_w_k, dim3(N3C / 64, Cc / 64), dim3(256), 0, stream,
                       w_attn, Wath, Watl, N3C, Cc);
    hipLaunchKernelGGL(cvt_w_k, dim3(Cc / 64, Cc / 64), dim3(256), 0, stream,
                       w_proj, Wph, Wpl, Cc, Cc);

    hipLaunchKernelGGL((mfma_gemm_k<true>), dim3(N3C / 128, Mm / 128), dim3(256),
                       0, stream, Xh, Xl, Wath, Watl, N3C, Cc,
                       cosT, sinT, Qh, Ql, Kh, Kl, Vth, Vtl, (float*)nullptr);

    hipLaunchKernelGGL(attn_mfma_k, dim3(Bb * NHh * 2), dim3(256), 0, stream,
                       Qh, Ql, Kh, Kl, Vth, Vtl, AOh, AOl);

    hipLaunchKernelGGL((mfma_gemm_k<false>), dim3(Cc / 128, Mm / 128), dim3(256),
                       0, stream, AOh, AOl, Wph, Wpl, Cc, Cc,
                       (const float*)nullptr, (const float*)nullptr,
                       (ushort*)nullptr, (ushort*)nullptr, (ushort*)nullptr,
                       (ushort*)nullptr, (ushort*)nullptr, (ushort*)nullptr, out);
}

// Round 5
// 240.025 us; speedup vs baseline: 2.6556x; 1.0795x over previous
//
#include <hip/hip_runtime.h>
#include <math.h>

#define Bb  64
#define Tt  256
#define Cc  384
#define NHh 6
#define HDd 64
#define N3C 1152
#define Mm  16384

typedef __attribute__((ext_vector_type(8))) short bf16x8;
typedef __attribute__((ext_vector_type(4))) float f32x4;

#define MFMA16(a, b, c) __builtin_amdgcn_mfma_f32_16x16x32_bf16((a), (b), (c), 0, 0, 0)

__device__ __forceinline__ ushort f2bf(float f) {
    uint u = __float_as_uint(f);
    u += 0x7fff + ((u >> 16) & 1);          // RNE
    return (ushort)(u >> 16);
}
__device__ __forceinline__ float bf2f(ushort h) {
    return __uint_as_float(((uint)h) << 16);
}
__device__ __forceinline__ uint cvtpk(float lo, float hi) {
    uint r;
    asm("v_cvt_pk_bf16_f32 %0, %1, %2" : "=v"(r) : "v"(lo), "v"(hi));
    return r;
}
__device__ __forceinline__ void gll16(const void* g, void* l) {
    __builtin_amdgcn_global_load_lds(
        (const __attribute__((address_space(1))) void*)g,
        (__attribute__((address_space(3))) void*)l, 16, 0, 0);
}

// ---------------- RoPE table ----------------
__global__ void rope_table_k(float* __restrict__ cosT, float* __restrict__ sinT) {
    int idx = blockIdx.x * 256 + threadIdx.x;   // 8192 total
    int t = idx >> 5;
    int i = idx & 31;
    float inv = powf(10000.0f, -(float)i / 32.0f);
    float ang = (float)t * inv;
    cosT[idx] = cosf(ang);
    sinT[idx] = sinf(ang);
}

// ---------------- x -> bf16 hi/lo split ----------------
__global__ __launch_bounds__(256)
void cvt_x_k(const float* __restrict__ x, ushort* __restrict__ Xh,
             ushort* __restrict__ Xl) {
    int i = (blockIdx.x * 256 + threadIdx.x) * 4;
    float4 v = *(const float4*)&x[i];
    float vv[4] = {v.x, v.y, v.z, v.w};
    ushort h[4], l[4];
#pragma unroll
    for (int j = 0; j < 4; ++j) {
        h[j] = f2bf(vv[j]);
        l[j] = f2bf(vv[j] - bf2f(h[j]));
    }
    *(uint2*)&Xh[i] = *(uint2*)h;
    *(uint2*)&Xl[i] = *(uint2*)l;
}

// ---------------- weight transpose + hi/lo split ----------------
__global__ __launch_bounds__(256)
void cvt_w_k(const float* __restrict__ w, ushort* __restrict__ Wth,
             ushort* __restrict__ Wtl, int N, int K) {
    int nl = threadIdx.x & 63, kb = threadIdx.x >> 6;
    int n  = blockIdx.x * 64 + nl;
    int k0 = blockIdx.y * 64 + kb * 16;
    ushort h[16], l[16];
#pragma unroll
    for (int j = 0; j < 16; ++j) {
        float v = w[(size_t)(k0 + j) * N + n];
        h[j] = f2bf(v);
        l[j] = f2bf(v - bf2f(h[j]));
    }
    size_t o = (size_t)n * K + k0;
    *(uint4*)&Wth[o]     = *(uint4*)&h[0];
    *(uint4*)&Wth[o + 8] = *(uint4*)&h[8];
    *(uint4*)&Wtl[o]     = *(uint4*)&l[0];
    *(uint4*)&Wtl[o + 8] = *(uint4*)&l[8];
}

// ---------------- split-bf16 MFMA GEMM (m97-structure staging) ----------
// global_load_lds width=16 into LINEAR LDS [128 rows][32 k] per array
// (conflict-free for both DMA writes and b128 fragment reads).
// 1-D grid, bijective XCD swizzle: xcd c owns A-panel rows [16c,16c+16).
template<bool ROPE>
__global__ __launch_bounds__(256)
void mfma_gemm_k(const ushort* __restrict__ Ah, const ushort* __restrict__ Al,
                 const ushort* __restrict__ Bth, const ushort* __restrict__ Btl,
                 int N, int K,
                 const float* __restrict__ cosT, const float* __restrict__ sinT,
                 ushort* __restrict__ Qh, ushort* __restrict__ Ql,
                 ushort* __restrict__ Kh, ushort* __restrict__ Kl,
                 ushort* __restrict__ Vth, ushort* __restrict__ Vtl,
                 float* __restrict__ outC)
{
    __shared__ ushort sAh[128*32], sAl[128*32], sBh[128*32], sBl[128*32];
    const int tid  = threadIdx.x;
    const int lane = tid & 63;
    const int wid  = tid >> 6;
    const int wm   = wid >> 1, wn = wid & 1;

    // XCD-swizzled block decode (grid = (N/128)*128 blocks, 1-D)
    const int nbx = N >> 7;
    const int xcd = blockIdx.x & 7;
    const int s   = blockIdx.x >> 3;
    const int m0  = (xcd * 16 + s / nbx) << 7;
    const int n0  = (s % nbx) << 7;

    // staging: wave w owns one array (8 chunks x 1KB; 16 rows/chunk)
    const ushort* gsrc = (wid == 0) ? Ah : (wid == 1) ? Al
                        : (wid == 2) ? Bth : Btl;
    ushort* ldst = (wid == 0) ? sAh : (wid == 1) ? sAl
                  : (wid == 2) ? sBh : sBl;
    const int row0 = (wid < 2) ? m0 : n0;
    const ushort* gbase = gsrc + (size_t)(row0 + (lane >> 2)) * K + (lane & 3) * 8;

    f32x4 acc[4][4];
#pragma unroll
    for (int i = 0; i < 4; ++i)
#pragma unroll
        for (int j = 0; j < 4; ++j) acc[i][j] = (f32x4){0.f, 0.f, 0.f, 0.f};

    const int kslot = (lane >> 4) * 8;
    const int rA = wm * 64 + (lane & 15);
    const int rB = wn * 64 + (lane & 15);

    for (int kc = 0; kc < K; kc += 32) {
        __syncthreads();                 // prev tile fully consumed
#pragma unroll
        for (int j = 0; j < 8; ++j)
            gll16(gbase + (size_t)j * 16 * K + kc, ldst + j * 512);
        asm volatile("s_waitcnt vmcnt(0)" ::: "memory");
        __syncthreads();                 // all arrays staged

        bf16x8 fa_h[4], fa_l[4], fb_h[4], fb_l[4];
#pragma unroll
        for (int f = 0; f < 4; ++f) {
            fa_h[f] = *(const bf16x8*)&sAh[(rA + f*16)*32 + kslot];
            fa_l[f] = *(const bf16x8*)&sAl[(rA + f*16)*32 + kslot];
            fb_h[f] = *(const bf16x8*)&sBh[(rB + f*16)*32 + kslot];
            fb_l[f] = *(const bf16x8*)&sBl[(rB + f*16)*32 + kslot];
        }
#pragma unroll
        for (int fm = 0; fm < 4; ++fm)
#pragma unroll
            for (int fn = 0; fn < 4; ++fn) {
                acc[fm][fn] = MFMA16(fa_h[fm], fb_h[fn], acc[fm][fn]);
                acc[fm][fn] = MFMA16(fa_h[fm], fb_l[fn], acc[fm][fn]);
                acc[fm][fn] = MFMA16(fa_l[fm], fb_h[fn], acc[fm][fn]);
            }
    }

    if (ROPE) {
#pragma unroll
        for (int fn = 0; fn < 4; ++fn) {
            int nglob = n0 + wn*64 + fn*16 + (lane & 15);
            int which = nglob / Cc;                 // wave-uniform
            int nloc  = nglob - which * Cc;
            int h = nloc >> 6, d = nloc & 63;
#pragma unroll
            for (int fm = 0; fm < 4; ++fm) {
                int mbase = m0 + wm*64 + fm*16 + ((lane >> 4) << 2);
                int b = mbase >> 8, t0 = mbase & 255;
                int bh = b * NHh + h;
                if (which == 2) {
                    ushort hv[4], lv[4];
#pragma unroll
                    for (int r = 0; r < 4; ++r) {
                        float v = acc[fm][fn][r];
                        hv[r] = f2bf(v);
                        lv[r] = f2bf(v - bf2f(hv[r]));
                    }
                    size_t o = ((size_t)bh * HDd + d) * Tt + t0;
                    *(uint2*)&Vth[o] = *(uint2*)hv;
                    *(uint2*)&Vtl[o] = *(uint2*)lv;
                } else {
#pragma unroll
                    for (int r = 0; r < 4; ++r) {
                        int t = t0 + r;
                        float v = acc[fm][fn][r];
                        float part = __shfl_xor(v, 1);
                        float cs = cosT[t*32 + (d >> 1)];
                        float sn = sinT[t*32 + (d >> 1)];
                        float nv = (d & 1) ? fmaf(v, cs,  part * sn)
                                           : fmaf(v, cs, -part * sn);
                        if (which == 0) nv *= 0.125f;
                        ushort hv = f2bf(nv);
                        ushort lv = f2bf(nv - bf2f(hv));
                        size_t o = ((size_t)bh * Tt + t) * HDd + d;
                        if (which == 0) { Qh[o] = hv; Ql[o] = lv; }
                        else            { Kh[o] = hv; Kl[o] = lv; }
                    }
                }
            }
        }
    } else {
#pragma unroll
        for (int fm = 0; fm < 4; ++fm)
#pragma unroll
            for (int fn = 0; fn < 4; ++fn) {
                int nglob = n0 + wn*64 + fn*16 + (lane & 15);
#pragma unroll
                for (int r = 0; r < 4; ++r) {
                    int m = m0 + wm*64 + fm*16 + ((lane >> 4) << 2) + r;
                    outC[(size_t)m * N + nglob] = acc[fm][fn][r];
                }
            }
    }
}

// ---------------- MFMA flash attention, causal, split-bf16 ----------------
__global__ __launch_bounds__(256, 3)
void attn_mfma_k(const ushort* __restrict__ Qh, const ushort* __restrict__ Ql,
                 const ushort* __restrict__ Kh, const ushort* __restrict__ Kl,
                 const ushort* __restrict__ Vth, const ushort* __restrict__ Vtl,
                 ushort* __restrict__ AOh, ushort* __restrict__ AOl)
{
    __shared__ ushort sP[4][2][512];        // [wave][hi/lo][16q x 32key] = 8KB
    const int e    = blockIdx.x & 1;
    const int bh   = blockIdx.x >> 1;
    const int wid  = threadIdx.x >> 6;
    const int lane = threadIdx.x & 63;
    const int q16  = lane & 15;
    const int g    = lane >> 4;

    const int b = bh / NHh, h = bh % NHh;
    char* pbh = (char*)&sP[wid][0][0];
    char* pbl = (char*)&sP[wid][1][0];
    const int xorq = (q16 & 3) << 4;

    const size_t qkbase = (size_t)bh * Tt * HDd;
    const size_t vtbase = (size_t)bh * HDd * Tt;

#pragma unroll
    for (int ti = 0; ti < 2; ++ti) {
        const int tile  = ti == 0 ? (e + 2*wid) : (e + 14 - 2*wid);
        const int qbase = tile * 16;
        const int nch   = (tile >> 1) + 1;

        bf16x8 fqh[2], fql[2];
        {
            const size_t qo = qkbase + (size_t)(qbase + q16) * HDd + 8*g;
            fqh[0] = *(const bf16x8*)&Qh[qo];
            fqh[1] = *(const bf16x8*)&Qh[qo + 32];
            fql[0] = *(const bf16x8*)&Ql[qo];
            fql[1] = *(const bf16x8*)&Ql[qo + 32];
        }
        f32x4 acc[4];
#pragma unroll
        for (int dt = 0; dt < 4; ++dt) acc[dt] = (f32x4){0.f, 0.f, 0.f, 0.f};
        float mx = -1e30f, lsum = 0.f;

        for (int c = 0; c < nch; ++c) {
            const int kb = c * 32;
            f32x4 S[2];
#pragma unroll
            for (int kt = 0; kt < 2; ++kt) {
                const size_t ko = qkbase + (size_t)(kb + 16*kt + q16) * HDd + 8*g;
                bf16x8 kh0 = *(const bf16x8*)&Kh[ko];
                bf16x8 kh1 = *(const bf16x8*)&Kh[ko + 32];
                bf16x8 kl0 = *(const bf16x8*)&Kl[ko];
                bf16x8 kl1 = *(const bf16x8*)&Kl[ko + 32];
                f32x4 s = (f32x4){0.f, 0.f, 0.f, 0.f};
                s = MFMA16(kh0, fqh[0], s);
                s = MFMA16(kh0, fql[0], s);
                s = MFMA16(kl0, fqh[0], s);
                s = MFMA16(kh1, fqh[1], s);
                s = MFMA16(kh1, fql[1], s);
                s = MFMA16(kl1, fqh[1], s);
                S[kt] = s;
            }
            const int q = qbase + q16;
#pragma unroll
            for (int kt = 0; kt < 2; ++kt)
#pragma unroll
                for (int r = 0; r < 4; ++r) {
                    int key = kb + 16*kt + 4*g + r;
                    S[kt][r] = (key <= q) ? S[kt][r] : -1e30f;
                }
            float pm = fmaxf(fmaxf(fmaxf(S[0][0], S[0][1]), fmaxf(S[0][2], S[0][3])),
                             fmaxf(fmaxf(S[1][0], S[1][1]), fmaxf(S[1][2], S[1][3])));
            pm = fmaxf(pm, __shfl_xor(pm, 16));
            pm = fmaxf(pm, __shfl_xor(pm, 32));
            float nm   = fmaxf(mx, pm);
            float resc = __expf(mx - nm);
            mx = nm;

            float p[2][4];
            float csum = 0.f;
#pragma unroll
            for (int kt = 0; kt < 2; ++kt)
#pragma unroll
                for (int r = 0; r < 4; ++r) {
                    p[kt][r] = __expf(S[kt][r] - nm);
                    csum += p[kt][r];
                }
            csum += __shfl_xor(csum, 16);
            csum += __shfl_xor(csum, 32);
            lsum = lsum * resc + csum;

            float rs[4];
#pragma unroll
            for (int r = 0; r < 4; ++r) rs[r] = __shfl(resc, 4*g + r);
#pragma unroll
            for (int dt = 0; dt < 4; ++dt)
#pragma unroll
                for (int r = 0; r < 4; ++r) acc[dt][r] *= rs[r];

#pragma unroll
            for (int kt = 0; kt < 2; ++kt) {
                uint a0 = cvtpk(p[kt][0], p[kt][1]);
                uint a1 = cvtpk(p[kt][2], p[kt][3]);
                float e0 = p[kt][0] - __uint_as_float(a0 << 16);
                float e1 = p[kt][1] - __uint_as_float(a0 & 0xffff0000u);
                float e2 = p[kt][2] - __uint_as_float(a1 << 16);
                float e3 = p[kt][3] - __uint_as_float(a1 & 0xffff0000u);
                uint b0 = cvtpk(e0, e1);
                uint b1 = cvtpk(e2, e3);
                int off = q16 * 64 + ((32*kt + 8*g) ^ xorq);
                *(uint2*)(pbh + off) = (uint2){a0, a1};
                *(uint2*)(pbl + off) = (uint2){b0, b1};
            }
            const int roff = q16 * 64 + ((16*g) ^ xorq);
            bf16x8 pah = *(const bf16x8*)(pbh + roff);
            bf16x8 pal = *(const bf16x8*)(pbl + roff);

#pragma unroll
            for (int dt = 0; dt < 4; ++dt) {
                const size_t vo = vtbase + (size_t)(16*dt + q16) * Tt + kb + 8*g;
                bf16x8 vh = *(const bf16x8*)&Vth[vo];
                bf16x8 vl = *(const bf16x8*)&Vtl[vo];
                acc[dt] = MFMA16(pah, vh, acc[dt]);
                acc[dt] = MFMA16(pah, vl, acc[dt]);
                acc[dt] = MFMA16(pal, vh, acc[dt]);
            }
        }

        float il[4];
#pragma unroll
        for (int r = 0; r < 4; ++r) il[r] = 1.0f / __shfl(lsum, 4*g + r);
#pragma unroll
        for (int dt = 0; dt < 4; ++dt) {
            int d = 16*dt + q16;
#pragma unroll
            for (int r = 0; r < 4; ++r) {
                int q = qbase + 4*g + r;
                float o = acc[dt][r] * il[r];
                ushort oh = f2bf(o);
                ushort ol = f2bf(o - bf2f(oh));
                size_t oo = ((size_t)(b * Tt + q)) * Cc + h * HDd + d;
                AOh[oo] = oh;
                AOl[oo] = ol;
            }
        }
    }
}

// ---------------- launcher ----------------
extern "C" void kernel_launch(void* const* d_in, const int* in_sizes, int n_in,
                              void* d_out, int out_size, void* d_ws, size_t ws_size,
                              hipStream_t stream) {
    (void)in_sizes; (void)n_in; (void)out_size; (void)ws_size;
    const float* x      = (const float*)d_in[0];
    const float* w_attn = (const float*)d_in[1];
    const float* w_proj = (const float*)d_in[2];
    float* out = (float*)d_out;

    const size_t SZ = (size_t)Bb * NHh * Tt * HDd;   // 6,291,456
    char* base = (char*)d_ws;
    float*  cosT = (float*)base;
    float*  sinT = cosT + 8192;
    ushort* Qh   = (ushort*)(base + 65536);
    ushort* Ql   = Qh + SZ;
    ushort* Kh   = Ql + SZ;
    ushort* Kl   = Kh + SZ;
    ushort* Vth  = Kl + SZ;
    ushort* Vtl  = Vth + SZ;
    ushort* Xh   = Vtl + SZ;
    ushort* Xl   = Xh + SZ;
    ushort* AOh  = Xh;                // alias: X dead after QKV GEMM
    ushort* AOl  = Xl;
    ushort* Wath = Xl + SZ;
    ushort* Watl = Wath + (size_t)N3C * Cc;
    ushort* Wph  = Watl + (size_t)N3C * Cc;
    ushort* Wpl  = Wph  + (size_t)Cc * Cc;

    hipLaunchKernelGGL(rope_table_k, dim3(32), dim3(256), 0, stream, cosT, sinT);
    hipLaunchKernelGGL(cvt_x_k, dim3(Mm * Cc / 1024), dim3(256), 0, stream,
                       x, Xh, Xl);
    hipLaunchKernelGGL(cvt_w_k, dim3(N3C / 64, Cc / 64), dim3(256), 0, stream,
                       w_attn, Wath, Watl, N3C, Cc);
    hipLaunchKernelGGL(cvt_w_k, dim3(Cc / 64, Cc / 64), dim3(256), 0, stream,
                       w_proj, Wph, Wpl, Cc, Cc);

    // 1-D grids for the XCD-swizzled GEMMs
    hipLaunchKernelGGL((mfma_gemm_k<true>), dim3((N3C / 128) * (Mm / 128)),
                       dim3(256), 0, stream, Xh, Xl, Wath, Watl, N3C, Cc,
                       cosT, sinT, Qh, Ql, Kh, Kl, Vth, Vtl, (float*)nullptr);

    hipLaunchKernelGGL(attn_mfma_k, dim3(Bb * NHh * 2), dim3(256), 0, stream,
                       Qh, Ql, Kh, Kl, Vth, Vtl, AOh, AOl);

    hipLaunchKernelGGL((mfma_gemm_k<false>), dim3((Cc / 128) * (Mm / 128)),
                       dim3(256), 0, stream, AOh, AOl, Wph, Wpl, Cc, Cc,
                       (const float*)nullptr, (const float*)nullptr,
                       (ushort*)nullptr, (ushort*)nullptr, (ushort*)nullptr,
                       (ushort*)nullptr, (ushort*)nullptr, (ushort*)nullptr, out);
}

// Round 6
// 234.680 us; speedup vs baseline: 2.7161x; 1.0228x over previous
//
#include <hip/hip_runtime.h>
#include <math.h>

#define Bb  64
#define Tt  256
#define Cc  384
#define NHh 6
#define HDd 64
#define N3C 1152
#define Mm  16384

typedef __attribute__((ext_vector_type(8))) short bf16x8;
typedef __attribute__((ext_vector_type(4))) float f32x4;

#define MFMA16(a, b, c) __builtin_amdgcn_mfma_f32_16x16x32_bf16((a), (b), (c), 0, 0, 0)

__device__ __forceinline__ ushort f2bf(float f) {
    uint u = __float_as_uint(f);
    u += 0x7fff + ((u >> 16) & 1);          // RNE
    return (ushort)(u >> 16);
}
__device__ __forceinline__ float bf2f(ushort h) {
    return __uint_as_float(((uint)h) << 16);
}
__device__ __forceinline__ uint cvtpk(float lo, float hi) {
    uint r;
    asm("v_cvt_pk_bf16_f32 %0, %1, %2" : "=v"(r) : "v"(lo), "v"(hi));
    return r;
}
__device__ __forceinline__ void gll16(const void* g, void* l) {
    __builtin_amdgcn_global_load_lds(
        (const __attribute__((address_space(1))) void*)g,
        (__attribute__((address_space(3))) void*)l, 16, 0, 0);
}

// ---------------- RoPE table ----------------
__global__ void rope_table_k(float* __restrict__ cosT, float* __restrict__ sinT) {
    int idx = blockIdx.x * 256 + threadIdx.x;   // 8192 total
    int t = idx >> 5;
    int i = idx & 31;
    float inv = powf(10000.0f, -(float)i / 32.0f);
    float ang = (float)t * inv;
    cosT[idx] = cosf(ang);
    sinT[idx] = sinf(ang);
}

// ---------------- x -> bf16 hi/lo split ----------------
__global__ __launch_bounds__(256)
void cvt_x_k(const float* __restrict__ x, ushort* __restrict__ Xh,
             ushort* __restrict__ Xl) {
    int i = (blockIdx.x * 256 + threadIdx.x) * 4;
    float4 v = *(const float4*)&x[i];
    float vv[4] = {v.x, v.y, v.z, v.w};
    ushort h[4], l[4];
#pragma unroll
    for (int j = 0; j < 4; ++j) {
        h[j] = f2bf(vv[j]);
        l[j] = f2bf(vv[j] - bf2f(h[j]));
    }
    *(uint2*)&Xh[i] = *(uint2*)h;
    *(uint2*)&Xl[i] = *(uint2*)l;
}

// ---------------- weight transpose + hi/lo split ----------------
__global__ __launch_bounds__(256)
void cvt_w_k(const float* __restrict__ w, ushort* __restrict__ Wth,
             ushort* __restrict__ Wtl, int N, int K) {
    int nl = threadIdx.x & 63, kb = threadIdx.x >> 6;
    int n  = blockIdx.x * 64 + nl;
    int k0 = blockIdx.y * 64 + kb * 16;
    ushort h[16], l[16];
#pragma unroll
    for (int j = 0; j < 16; ++j) {
        float v = w[(size_t)(k0 + j) * N + n];
        h[j] = f2bf(v);
        l[j] = f2bf(v - bf2f(h[j]));
    }
    size_t o = (size_t)n * K + k0;
    *(uint4*)&Wth[o]     = *(uint4*)&h[0];
    *(uint4*)&Wth[o + 8] = *(uint4*)&h[8];
    *(uint4*)&Wtl[o]     = *(uint4*)&l[0];
    *(uint4*)&Wtl[o + 8] = *(uint4*)&l[8];
}

// ---------------- split-bf16 MFMA GEMM, double-buffered ----------------
// Tile (32*MF) x 128, 4 waves (2x2), BK=32. global_load_lds width=16,
// linear LDS dest; bank-swizzle via PRE-SWIZZLED GLOBAL source
// (seg' = seg ^ (row&3)) matched by XOR on the fragment read (rule 21).
// 2-phase pipeline: stage tile k+1 into buf^1 before computing tile k,
// single vmcnt(0)+barrier per K-step placed AFTER the MFMAs.
template<bool ROPE, int MF>
__global__ __launch_bounds__(256)
void mfma_gemm_k(const ushort* __restrict__ Ah, const ushort* __restrict__ Al,
                 const ushort* __restrict__ Bth, const ushort* __restrict__ Btl,
                 int N, int K,
                 const float* __restrict__ cosT, const float* __restrict__ sinT,
                 ushort* __restrict__ Qh, ushort* __restrict__ Ql,
                 ushort* __restrict__ Kh, ushort* __restrict__ Kl,
                 ushort* __restrict__ Vth, ushort* __restrict__ Vtl,
                 float* __restrict__ outC)
{
    __shared__ ushort sAh[2][1024*MF], sAl[2][1024*MF];
    __shared__ ushort sBh[2][4096],    sBl[2][4096];
    const int tid  = threadIdx.x;
    const int lane = tid & 63;
    const int wid  = tid >> 6;
    const int wm   = wid >> 1, wn = wid & 1;

    // XCD-swizzled 1-D block decode (bijective: gridDim % 8 == 0)
    const int nbx = N >> 7;
    const int xcd = blockIdx.x & 7;
    const int s   = blockIdx.x >> 3;
    const int mpx = (int)(gridDim.x >> 3) / nbx;        // m-panels per xcd
    const int m0  = (xcd * mpx + s / nbx) * (32 * MF);
    const int n0  = (s % nbx) << 7;

    // staging: wave w owns one array; A-waves 2*MF chunks, B-waves 8
    const ushort* gsrc = (wid == 0) ? Ah : (wid == 1) ? Al
                        : (wid == 2) ? Bth : Btl;
    ushort* lbase = (wid == 0) ? &sAh[0][0] : (wid == 1) ? &sAl[0][0]
                   : (wid == 2) ? &sBh[0][0] : &sBl[0][0];
    const int lstride = (wid < 2) ? 1024*MF : 4096;
    const int nchunk  = (wid < 2) ? 2*MF : 8;
    const int row0 = (wid < 2) ? m0 : n0;
    // pre-swizzled global source: seg' = seg ^ (row&3)
    const ushort* gbase = gsrc + (size_t)(row0 + (lane >> 2)) * K
                          + (size_t)(((lane & 3) ^ ((lane >> 2) & 3)) * 8);

#define STAGE(buf, kc)                                                     \
    for (int j = 0; j < nchunk; ++j)                                       \
        gll16(gbase + (size_t)j * 16 * K + (kc), lbase + (buf)*lstride + j*512);

    f32x4 acc[MF][4];
#pragma unroll
    for (int i = 0; i < MF; ++i)
#pragma unroll
        for (int j = 0; j < 4; ++j) acc[i][j] = (f32x4){0.f, 0.f, 0.f, 0.f};

    // fragment read coords (swizzled k-slot; row&3 == lane&3 for all frags)
    const int kswz = (((lane >> 4) ^ (lane & 3)) * 8);
    const int rA = wm * (16*MF) + (lane & 15);
    const int rB = wn * 64 + (lane & 15);

    STAGE(0, 0)
    asm volatile("s_waitcnt vmcnt(0)" ::: "memory");
    __syncthreads();

    for (int kc = 0; kc < K; kc += 32) {
        const int cur = (kc >> 5) & 1;
        if (kc + 32 < K) STAGE(cur ^ 1, kc + 32)

        bf16x8 fa_h[MF], fa_l[MF], fb_h[4], fb_l[4];
#pragma unroll
        for (int f = 0; f < MF; ++f) {
            fa_h[f] = *(const bf16x8*)&sAh[cur][(rA + f*16)*32 + kswz];
            fa_l[f] = *(const bf16x8*)&sAl[cur][(rA + f*16)*32 + kswz];
        }
#pragma unroll
        for (int f = 0; f < 4; ++f) {
            fb_h[f] = *(const bf16x8*)&sBh[cur][(rB + f*16)*32 + kswz];
            fb_l[f] = *(const bf16x8*)&sBl[cur][(rB + f*16)*32 + kswz];
        }
#pragma unroll
        for (int fm = 0; fm < MF; ++fm)
#pragma unroll
            for (int fn = 0; fn < 4; ++fn) {
                acc[fm][fn] = MFMA16(fa_h[fm], fb_h[fn], acc[fm][fn]);
                acc[fm][fn] = MFMA16(fa_h[fm], fb_l[fn], acc[fm][fn]);
                acc[fm][fn] = MFMA16(fa_l[fm], fb_h[fn], acc[fm][fn]);
            }
        asm volatile("s_waitcnt vmcnt(0)" ::: "memory");
        __syncthreads();
    }
#undef STAGE

    if (ROPE) {
#pragma unroll
        for (int fn = 0; fn < 4; ++fn) {
            int nglob = n0 + wn*64 + fn*16 + (lane & 15);
            int which = nglob / Cc;                 // wave-uniform
            int nloc  = nglob - which * Cc;
            int h = nloc >> 6, d = nloc & 63;
#pragma unroll
            for (int fm = 0; fm < MF; ++fm) {
                int mbase = m0 + wm*(16*MF) + fm*16 + ((lane >> 4) << 2);
                int b = mbase >> 8, t0 = mbase & 255;
                int bh = b * NHh + h;
                if (which == 2) {
                    ushort hv[4], lv[4];
#pragma unroll
                    for (int r = 0; r < 4; ++r) {
                        float v = acc[fm][fn][r];
                        hv[r] = f2bf(v);
                        lv[r] = f2bf(v - bf2f(hv[r]));
                    }
                    size_t o = ((size_t)bh * HDd + d) * Tt + t0;
                    *(uint2*)&Vth[o] = *(uint2*)hv;
                    *(uint2*)&Vtl[o] = *(uint2*)lv;
                } else {
#pragma unroll
                    for (int r = 0; r < 4; ++r) {
                        int t = t0 + r;
                        float v = acc[fm][fn][r];
                        float part = __shfl_xor(v, 1);
                        float cs = cosT[t*32 + (d >> 1)];
                        float sn = sinT[t*32 + (d >> 1)];
                        float nv = (d & 1) ? fmaf(v, cs,  part * sn)
                                           : fmaf(v, cs, -part * sn);
                        if (which == 0) nv *= 0.125f;
                        ushort hv = f2bf(nv);
                        ushort lv = f2bf(nv - bf2f(hv));
                        size_t o = ((size_t)bh * Tt + t) * HDd + d;
                        if (which == 0) { Qh[o] = hv; Ql[o] = lv; }
                        else            { Kh[o] = hv; Kl[o] = lv; }
                    }
                }
            }
        }
    } else {
#pragma unroll
        for (int fm = 0; fm < MF; ++fm)
#pragma unroll
            for (int fn = 0; fn < 4; ++fn) {
                int nglob = n0 + wn*64 + fn*16 + (lane & 15);
#pragma unroll
                for (int r = 0; r < 4; ++r) {
                    int m = m0 + wm*(16*MF) + fm*16 + ((lane >> 4) << 2) + r;
                    outC[(size_t)m * N + nglob] = acc[fm][fn][r];
                }
            }
    }
}

// ---------------- MFMA flash attention, causal, split-bf16 ----------------
__global__ __launch_bounds__(256, 3)
void attn_mfma_k(const ushort* __restrict__ Qh, const ushort* __restrict__ Ql,
                 const ushort* __restrict__ Kh, const ushort* __restrict__ Kl,
                 const ushort* __restrict__ Vth, const ushort* __restrict__ Vtl,
                 ushort* __restrict__ AOh, ushort* __restrict__ AOl)
{
    __shared__ ushort sP[4][2][512];        // [wave][hi/lo][16q x 32key] = 8KB
    const int e    = blockIdx.x & 1;
    const int bh   = blockIdx.x >> 1;
    const int wid  = threadIdx.x >> 6;
    const int lane = threadIdx.x & 63;
    const int q16  = lane & 15;
    const int g    = lane >> 4;

    const int b = bh / NHh, h = bh % NHh;
    char* pbh = (char*)&sP[wid][0][0];
    char* pbl = (char*)&sP[wid][1][0];
    const int xorq = (q16 & 3) << 4;

    const size_t qkbase = (size_t)bh * Tt * HDd;
    const size_t vtbase = (size_t)bh * HDd * Tt;

#pragma unroll
    for (int ti = 0; ti < 2; ++ti) {
        const int tile  = ti == 0 ? (e + 2*wid) : (e + 14 - 2*wid);
        const int qbase = tile * 16;
        const int nch   = (tile >> 1) + 1;

        bf16x8 fqh[2], fql[2];
        {
            const size_t qo = qkbase + (size_t)(qbase + q16) * HDd + 8*g;
            fqh[0] = *(const bf16x8*)&Qh[qo];
            fqh[1] = *(const bf16x8*)&Qh[qo + 32];
            fql[0] = *(const bf16x8*)&Ql[qo];
            fql[1] = *(const bf16x8*)&Ql[qo + 32];
        }
        f32x4 acc[4];
#pragma unroll
        for (int dt = 0; dt < 4; ++dt) acc[dt] = (f32x4){0.f, 0.f, 0.f, 0.f};
        float mx = -1e30f, lsum = 0.f;

        for (int c = 0; c < nch; ++c) {
            const int kb = c * 32;
            f32x4 S[2];
#pragma unroll
            for (int kt = 0; kt < 2; ++kt) {
                const size_t ko = qkbase + (size_t)(kb + 16*kt + q16) * HDd + 8*g;
                bf16x8 kh0 = *(const bf16x8*)&Kh[ko];
                bf16x8 kh1 = *(const bf16x8*)&Kh[ko + 32];
                bf16x8 kl0 = *(const bf16x8*)&Kl[ko];
                bf16x8 kl1 = *(const bf16x8*)&Kl[ko + 32];
                f32x4 s = (f32x4){0.f, 0.f, 0.f, 0.f};
                s = MFMA16(kh0, fqh[0], s);
                s = MFMA16(kh0, fql[0], s);
                s = MFMA16(kl0, fqh[0], s);
                s = MFMA16(kh1, fqh[1], s);
                s = MFMA16(kh1, fql[1], s);
                s = MFMA16(kl1, fqh[1], s);
                S[kt] = s;
            }
            const int q = qbase + q16;
#pragma unroll
            for (int kt = 0; kt < 2; ++kt)
#pragma unroll
                for (int r = 0; r < 4; ++r) {
                    int key = kb + 16*kt + 4*g + r;
                    S[kt][r] = (key <= q) ? S[kt][r] : -1e30f;
                }
            float pm = fmaxf(fmaxf(fmaxf(S[0][0], S[0][1]), fmaxf(S[0][2], S[0][3])),
                             fmaxf(fmaxf(S[1][0], S[1][1]), fmaxf(S[1][2], S[1][3])));
            pm = fmaxf(pm, __shfl_xor(pm, 16));
            pm = fmaxf(pm, __shfl_xor(pm, 32));
            float nm   = fmaxf(mx, pm);
            float resc = __expf(mx - nm);
            mx = nm;

            float p[2][4];
            float csum = 0.f;
#pragma unroll
            for (int kt = 0; kt < 2; ++kt)
#pragma unroll
                for (int r = 0; r < 4; ++r) {
                    p[kt][r] = __expf(S[kt][r] - nm);
                    csum += p[kt][r];
                }
            csum += __shfl_xor(csum, 16);
            csum += __shfl_xor(csum, 32);
            lsum = lsum * resc + csum;

            float rs[4];
#pragma unroll
            for (int r = 0; r < 4; ++r) rs[r] = __shfl(resc, 4*g + r);
#pragma unroll
            for (int dt = 0; dt < 4; ++dt)
#pragma unroll
                for (int r = 0; r < 4; ++r) acc[dt][r] *= rs[r];

#pragma unroll
            for (int kt = 0; kt < 2; ++kt) {
                uint a0 = cvtpk(p[kt][0], p[kt][1]);
                uint a1 = cvtpk(p[kt][2], p[kt][3]);
                float e0 = p[kt][0] - __uint_as_float(a0 << 16);
                float e1 = p[kt][1] - __uint_as_float(a0 & 0xffff0000u);
                float e2 = p[kt][2] - __uint_as_float(a1 << 16);
                float e3 = p[kt][3] - __uint_as_float(a1 & 0xffff0000u);
                uint b0 = cvtpk(e0, e1);
                uint b1 = cvtpk(e2, e3);
                int off = q16 * 64 + ((32*kt + 8*g) ^ xorq);
                *(uint2*)(pbh + off) = (uint2){a0, a1};
                *(uint2*)(pbl + off) = (uint2){b0, b1};
            }
            const int roff = q16 * 64 + ((16*g) ^ xorq);
            bf16x8 pah = *(const bf16x8*)(pbh + roff);
            bf16x8 pal = *(const bf16x8*)(pbl + roff);

#pragma unroll
            for (int dt = 0; dt < 4; ++dt) {
                const size_t vo = vtbase + (size_t)(16*dt + q16) * Tt + kb + 8*g;
                bf16x8 vh = *(const bf16x8*)&Vth[vo];
                bf16x8 vl = *(const bf16x8*)&Vtl[vo];
                acc[dt] = MFMA16(pah, vh, acc[dt]);
                acc[dt] = MFMA16(pah, vl, acc[dt]);
                acc[dt] = MFMA16(pal, vh, acc[dt]);
            }
        }

        float il[4];
#pragma unroll
        for (int r = 0; r < 4; ++r) il[r] = 1.0f / __shfl(lsum, 4*g + r);
#pragma unroll
        for (int dt = 0; dt < 4; ++dt) {
            int d = 16*dt + q16;
#pragma unroll
            for (int r = 0; r < 4; ++r) {
                int q = qbase + 4*g + r;
                float o = acc[dt][r] * il[r];
                ushort oh = f2bf(o);
                ushort ol = f2bf(o - bf2f(oh));
                size_t oo = ((size_t)(b * Tt + q)) * Cc + h * HDd + d;
                AOh[oo] = oh;
                AOl[oo] = ol;
            }
        }
    }
}

// ---------------- launcher ----------------
extern "C" void kernel_launch(void* const* d_in, const int* in_sizes, int n_in,
                              void* d_out, int out_size, void* d_ws, size_t ws_size,
                              hipStream_t stream) {
    (void)in_sizes; (void)n_in; (void)out_size; (void)ws_size;
    const float* x      = (const float*)d_in[0];
    const float* w_attn = (const float*)d_in[1];
    const float* w_proj = (const float*)d_in[2];
    float* out = (float*)d_out;

    const size_t SZ = (size_t)Bb * NHh * Tt * HDd;   // 6,291,456
    char* base = (char*)d_ws;
    float*  cosT = (float*)base;
    float*  sinT = cosT + 8192;
    ushort* Qh   = (ushort*)(base + 65536);
    ushort* Ql   = Qh + SZ;
    ushort* Kh   = Ql + SZ;
    ushort* Kl   = Kh + SZ;
    ushort* Vth  = Kl + SZ;
    ushort* Vtl  = Vth + SZ;
    ushort* Xh   = Vtl + SZ;
    ushort* Xl   = Xh + SZ;
    ushort* AOh  = Xh;                // alias: X dead after QKV GEMM
    ushort* AOl  = Xl;
    ushort* Wath = Xl + SZ;
    ushort* Watl = Wath + (size_t)N3C * Cc;
    ushort* Wph  = Watl + (size_t)N3C * Cc;
    ushort* Wpl  = Wph  + (size_t)Cc * Cc;

    hipLaunchKernelGGL(rope_table_k, dim3(32), dim3(256), 0, stream, cosT, sinT);
    hipLaunchKernelGGL(cvt_x_k, dim3(Mm * Cc / 1024), dim3(256), 0, stream,
                       x, Xh, Xl);
    hipLaunchKernelGGL(cvt_w_k, dim3(N3C / 64, Cc / 64), dim3(256), 0, stream,
                       w_attn, Wath, Watl, N3C, Cc);
    hipLaunchKernelGGL(cvt_w_k, dim3(Cc / 64, Cc / 64), dim3(256), 0, stream,
                       w_proj, Wph, Wpl, Cc, Cc);

    // QKV: 128x128 tiles (MF=4), grid 9*128 = 1152 (div by 8)
    hipLaunchKernelGGL((mfma_gemm_k<true, 4>), dim3((N3C / 128) * (Mm / 128)),
                       dim3(256), 0, stream, Xh, Xl, Wath, Watl, N3C, Cc,
                       cosT, sinT, Qh, Ql, Kh, Kl, Vth, Vtl, (float*)nullptr);

    hipLaunchKernelGGL(attn_mfma_k, dim3(Bb * NHh * 2), dim3(256), 0, stream,
                       Qh, Ql, Kh, Kl, Vth, Vtl, AOh, AOl);

    // proj: 64x128 tiles (MF=2), grid 3*256 = 768 (div by 8)
    hipLaunchKernelGGL((mfma_gemm_k<false, 2>), dim3((Cc / 128) * (Mm / 64)),
                       dim3(256), 0, stream, AOh, AOl, Wph, Wpl, Cc, Cc,
                       (const float*)nullptr, (const float*)nullptr,
                       (ushort*)nullptr, (ushort*)nullptr, (ushort*)nullptr,
                       (ushort*)nullptr, (ushort*)nullptr, (ushort*)nullptr, out);
}